// Round 5
// baseline (1020.891 us; speedup 1.0000x reference)
//
#include <hip/hip_runtime.h>
#include <hip/hip_bf16.h>
#include <math.h>

#define Bdim 8
#define Tdim 1024
#define Cdim 768
#define Hdim 24
#define Ndim 32
#define BTdim (Bdim*Tdim)
#define CH6 16

typedef __attribute__((ext_vector_type(8))) short bf16x8;
typedef __attribute__((ext_vector_type(4))) float f32x4;

__device__ __forceinline__ float sigm(float x){ return 1.f/(1.f+expf(-x)); }
__device__ __forceinline__ float softplusf(float x){ return fmaxf(x,0.f) + log1pf(expf(-fabsf(x))); }

template<int CTRL>
__device__ __forceinline__ float dpp_add(float x){
  int xi = __builtin_bit_cast(int, x);
  int yi = __builtin_amdgcn_mov_dpp(xi, CTRL, 0xF, 0xF, true);
  return x + __builtin_bit_cast(float, yi);
}
// sum over each 32-lane half (all lanes receive the result)
__device__ __forceinline__ float red32(float x){
  x = dpp_add<0xB1>(x);    // quad xor1
  x = dpp_add<0x4E>(x);    // quad xor2
  x = dpp_add<0x141>(x);   // row_half_mirror -> 8-lane sums
  x = dpp_add<0x140>(x);   // row_mirror -> 16-lane sums
  x += __shfl_xor(x, 16);  // -> 32-lane sums
  return x;
}

#define GLDS16(gp, lp) __builtin_amdgcn_global_load_lds((const __attribute__((address_space(1))) void*)(gp), (__attribute__((address_space(3))) void*)(lp), 16, 0, 0)

// ---------------- K1: token shift ----------------
__global__ void k1_shift(const float* __restrict__ x, const float* __restrict__ maa_x,
                         float* __restrict__ xx, __hip_bfloat16* __restrict__ xxx) {
  int idx = blockIdx.x*256 + threadIdx.x;
  if (idx >= BTdim*Cdim) return;
  int c = idx % Cdim; int row = idx / Cdim; int t = row % Tdim;
  float xv = x[idx];
  float xp = (t==0) ? 0.f : x[idx - Cdim];
  float d = xp - xv;
  xx[idx] = d;
  xxx[idx] = __float2bfloat16(xv + d*maa_x[c]);
}

// ---------------- big weight convert + transpose ----------------
__global__ __launch_bounds__(256) void kconvW(const float* __restrict__ W0, const float* __restrict__ W1,
    const float* __restrict__ W2, const float* __restrict__ W3,
    __hip_bfloat16* __restrict__ T0, __hip_bfloat16* __restrict__ T1,
    __hip_bfloat16* __restrict__ T2, __hip_bfloat16* __restrict__ T3) {
  const float* Wsrc[4] = {W0,W1,W2,W3};
  __hip_bfloat16* Tdst[4] = {T0,T1,T2,T3};
  const float* W = Wsrc[blockIdx.z];
  __hip_bfloat16* T = Tdst[blockIdx.z];
  __shared__ float tile[32][33];
  int bx = blockIdx.x*32, by = blockIdx.y*32;
  int tx = threadIdx.x & 31, ty = threadIdx.x >> 5;
  #pragma unroll
  for (int q=0;q<32;q+=8) tile[ty+q][tx] = W[(size_t)(by+ty+q)*Cdim + bx+tx];
  __syncthreads();
  #pragma unroll
  for (int q=0;q<32;q+=8) T[(size_t)(bx+ty+q)*Cdim + by+tx] = __float2bfloat16(tile[tx][ty+q]);
}

// ---------------- small-weight pack: transposed bf16 padded to [128][768] ----------------
__global__ __launch_bounds__(256) void kprep(const float* __restrict__ dw1, const float* __restrict__ aaa_w1,
    const float* __restrict__ ma_w1, const float* __restrict__ kkk_w1, const float* __restrict__ mk_w1,
    const float* __restrict__ mv_w1, const float* __restrict__ gate_w1, const float* __restrict__ maa_w1,
    __hip_bfloat16* __restrict__ PWwa, __hip_bfloat16* __restrict__ PWk, __hip_bfloat16* __restrict__ PWv,
    __hip_bfloat16* __restrict__ PWrg, __hip_bfloat16* __restrict__ PWmaa){
  int idx = blockIdx.x*256 + threadIdx.x;
  if (idx >= 5*128*768) return;
  int buf = idx / 98304, rem = idx - buf*98304;
  int n = rem / 768, kk = rem - n*768;
  float val = 0.f;
  __hip_bfloat16* dst;
  switch(buf){
    case 0: dst=PWwa; if(n<64) val=dw1[(size_t)kk*64+n]; else if(n<88) val=aaa_w1[(size_t)kk*24+(n-64)]; else if(n<112) val=ma_w1[(size_t)kk*24+(n-88)]; break;
    case 1: dst=PWk;  if(n<24) val=kkk_w1[(size_t)kk*24+n]; else if(n<48) val=mk_w1[(size_t)kk*24+(n-24)]; break;
    case 2: dst=PWv;  if(n<24) val=mv_w1[(size_t)kk*24+n]; break;
    case 3: dst=PWrg; if(n<120) val=gate_w1[(size_t)kk*120+n]; break;
    default: dst=PWmaa; if(n<112) val=maa_w1[(size_t)kk*112+n]; break;
  }
  dst[rem] = __float2bfloat16(val);
}

// ---------------- bf16 MFMA GEMM (m97 structure), big matrices, no act ----------------
__global__ __launch_bounds__(256) void gemm_mfma(const __hip_bfloat16* __restrict__ A,
    const __hip_bfloat16* __restrict__ Bt, float* __restrict__ C, int M, int N, int K) {
  __shared__ unsigned short As[128*32];
  __shared__ unsigned short Bs[128*32];
  const int bm = blockIdx.y*128, bn = blockIdx.x*128;
  const int tid = threadIdx.x, lane = tid&63, w = tid>>6;
  const int wr = w>>1, wc = w&1;
  const int lr = lane&15, kg = lane>>4;
  f32x4 zero = {0.f,0.f,0.f,0.f};
  f32x4 acc[4][4];
  #pragma unroll
  for (int m=0;m<4;m++)
    #pragma unroll
    for (int n=0;n<4;n++) acc[m][n]=zero;
  const size_t rowA = (size_t)(bm + w*32 + (lane>>2))*K + (lane&3)*8;
  const size_t rowB = (size_t)(bn + w*32 + (lane>>2))*K + (lane&3)*8;
  unsigned short* lA = As + w*32*32;
  unsigned short* lB = Bs + w*32*32;
  for (int k0=0; k0<K; k0+=32){
    GLDS16(A + rowA + k0,                 lA);
    GLDS16(A + rowA + k0 + (size_t)16*K,  lA + 512);
    GLDS16(Bt + rowB + k0,                lB);
    GLDS16(Bt + rowB + k0 + (size_t)16*K, lB + 512);
    __syncthreads();
    bf16x8 af[4], bfr[4];
    #pragma unroll
    for (int m=0;m<4;m++) af[m]  = *(const bf16x8*)(void*)(As + (wr*64+m*16+lr)*32 + kg*8);
    #pragma unroll
    for (int n=0;n<4;n++) bfr[n] = *(const bf16x8*)(void*)(Bs + (wc*64+n*16+lr)*32 + kg*8);
    #pragma unroll
    for (int m=0;m<4;m++)
      #pragma unroll
      for (int n=0;n<4;n++)
        acc[m][n] = __builtin_amdgcn_mfma_f32_16x16x32_bf16(af[m], bfr[n], acc[m][n], 0,0,0);
    __syncthreads();
  }
  #pragma unroll
  for (int m=0;m<4;m++)
    #pragma unroll
    for (int n=0;n<4;n++){
      size_t r0 = (size_t)(bm + wr*64 + m*16 + kg*4);
      int cc = bn + wc*64 + n*16 + lr;
      #pragma unroll
      for (int q=0;q<4;q++)
        C[(r0+q)*N + cc] = acc[m][n][q];
    }
}

// ---------------- batched small MFMA GEMM with runtime per-z activation ----------------
// act: 0 none; 1 tanh if col<64; 2 tanh if col<24; 3 sigm all; 4 tanh all
struct G4 {
  const __hip_bfloat16* A[4];
  const __hip_bfloat16* Bt[4];
  float* C[4];
  int N[4];
  int act[4];
};
__global__ __launch_bounds__(256) void gemm_small(G4 p, int K) {
  const int z = blockIdx.z;
  const __hip_bfloat16* __restrict__ A  = p.A[z];
  const __hip_bfloat16* __restrict__ Bt = p.Bt[z];
  float* __restrict__ C = p.C[z];
  const int N = p.N[z], act = p.act[z];
  __shared__ unsigned short As[128*32];
  __shared__ unsigned short Bs[128*32];
  const int bm = blockIdx.y*128, bn = 0;
  const int tid = threadIdx.x, lane = tid&63, w = tid>>6;
  const int wr = w>>1, wc = w&1;
  const int lr = lane&15, kg = lane>>4;
  f32x4 zero = {0.f,0.f,0.f,0.f};
  f32x4 acc[4][4];
  #pragma unroll
  for (int m=0;m<4;m++)
    #pragma unroll
    for (int n=0;n<4;n++) acc[m][n]=zero;
  const size_t rowA = (size_t)(bm + w*32 + (lane>>2))*K + (lane&3)*8;
  const size_t rowB = (size_t)(bn + w*32 + (lane>>2))*K + (lane&3)*8;
  unsigned short* lA = As + w*32*32;
  unsigned short* lB = Bs + w*32*32;
  for (int k0=0; k0<K; k0+=32){
    GLDS16(A + rowA + k0,                 lA);
    GLDS16(A + rowA + k0 + (size_t)16*K,  lA + 512);
    GLDS16(Bt + rowB + k0,                lB);
    GLDS16(Bt + rowB + k0 + (size_t)16*K, lB + 512);
    __syncthreads();
    bf16x8 af[4], bfr[4];
    #pragma unroll
    for (int m=0;m<4;m++) af[m]  = *(const bf16x8*)(void*)(As + (wr*64+m*16+lr)*32 + kg*8);
    #pragma unroll
    for (int n=0;n<4;n++) bfr[n] = *(const bf16x8*)(void*)(Bs + (wc*64+n*16+lr)*32 + kg*8);
    #pragma unroll
    for (int m=0;m<4;m++)
      #pragma unroll
      for (int n=0;n<4;n++)
        acc[m][n] = __builtin_amdgcn_mfma_f32_16x16x32_bf16(af[m], bfr[n], acc[m][n], 0,0,0);
    __syncthreads();
  }
  #pragma unroll
  for (int m=0;m<4;m++)
    #pragma unroll
    for (int n=0;n<4;n++){
      size_t r0 = (size_t)(bm + wr*64 + m*16 + kg*4);
      int cc = bn + wc*64 + n*16 + lr;
      if (cc < N) {
        #pragma unroll
        for (int q=0;q<4;q++){
          float val = acc[m][n][q];
          if      (act==1){ if (cc<64) val = tanhf(val); }
          else if (act==2){ if (cc<24) val = tanhf(val); }
          else if (act==3){ val = sigm(val); }
          else if (act==4){ val = tanhf(val); }
          C[(r0+q)*N + cc] = val;
        }
      }
    }
}

// ---------------- K2b: mix, 8 rows per block; float4 broadcast LDS reads (tm pre-tanh'd) ----------------
__global__ __launch_bounds__(256) void k2_mix(const float* __restrict__ x, const float* __restrict__ xx,
    const float* __restrict__ tm, const float* __restrict__ w2,
    const float* __restrict__ mrg, const float* __restrict__ mwa,
    const float* __restrict__ mk_, const float* __restrict__ mv_,
    __hip_bfloat16* __restrict__ xrg, __hip_bfloat16* __restrict__ xwa,
    __hip_bfloat16* __restrict__ xk, __hip_bfloat16* __restrict__ xv) {
  const int row0 = blockIdx.x*8, tid = threadIdx.x;
  __shared__ float stm[8][112];
  for (int idx=tid; idx<8*28; idx+=256){
    int rr=idx/28, q4=idx-rr*28;
    *(float4*)&stm[rr][q4*4] = *(const float4*)&tm[(size_t)(row0+rr)*112+q4*4];
  }
  __syncthreads();
  #pragma unroll
  for (int it=0; it<3; it++){
    const int c = tid + it*256;
    float x8[8], d8[8];
    #pragma unroll
    for (int rr=0;rr<8;rr++){
      size_t i=(size_t)(row0+rr)*Cdim+c;
      x8[rr]=x[i]; d8[rr]=xx[i];
    }
    float m0[8]={},m1[8]={},m2[8]={},m3[8]={};
    #pragma unroll 1
    for (int d4=0; d4<7; d4++){
      const int d = d4*4;
      float w0a=w2[(size_t)(d+0)*Cdim+c], w0b=w2[(size_t)(d+1)*Cdim+c], w0c=w2[(size_t)(d+2)*Cdim+c], w0d=w2[(size_t)(d+3)*Cdim+c];
      float w1a=w2[(size_t)(28+d+0)*Cdim+c], w1b=w2[(size_t)(28+d+1)*Cdim+c], w1c=w2[(size_t)(28+d+2)*Cdim+c], w1d=w2[(size_t)(28+d+3)*Cdim+c];
      float w2a=w2[(size_t)(56+d+0)*Cdim+c], w2b=w2[(size_t)(56+d+1)*Cdim+c], w2c=w2[(size_t)(56+d+2)*Cdim+c], w2d=w2[(size_t)(56+d+3)*Cdim+c];
      float w3a=w2[(size_t)(84+d+0)*Cdim+c], w3b=w2[(size_t)(84+d+1)*Cdim+c], w3c=w2[(size_t)(84+d+2)*Cdim+c], w3d=w2[(size_t)(84+d+3)*Cdim+c];
      #pragma unroll
      for (int rr=0;rr<8;rr++){
        float4 h0 = *(const float4*)&stm[rr][d];
        float4 h1 = *(const float4*)&stm[rr][28+d];
        float4 h2 = *(const float4*)&stm[rr][56+d];
        float4 h3 = *(const float4*)&stm[rr][84+d];
        m0[rr] += h0.x*w0a + h0.y*w0b + h0.z*w0c + h0.w*w0d;
        m1[rr] += h1.x*w1a + h1.y*w1b + h1.z*w1c + h1.w*w1d;
        m2[rr] += h2.x*w2a + h2.y*w2b + h2.z*w2c + h2.w*w2d;
        m3[rr] += h3.x*w3a + h3.y*w3b + h3.z*w3c + h3.w*w3d;
      }
    }
    float mrgc=mrg[c], mwac=mwa[c], mkc=mk_[c], mvc=mv_[c];
    #pragma unroll
    for (int rr=0;rr<8;rr++){
      size_t i=(size_t)(row0+rr)*Cdim+c;
      xrg[i]=__float2bfloat16(x8[rr] + d8[rr]*(mrgc+m0[rr]));
      xwa[i]=__float2bfloat16(x8[rr] + d8[rr]*(mwac+m1[rr]));
      xk[i] =__float2bfloat16(x8[rr] + d8[rr]*(mkc+m2[rr]));
      xv[i] =__float2bfloat16(x8[rr] + d8[rr]*(mvc+m3[rr]));
    }
  }
}

// ---------------- K5 v2: registers + in-wave head norm; float4 broadcast LDS reads ----------------
// h buffers arrive PRE-ACTIVATED (gemm_small epilogue). sall row layout:
// [0:112) hwa (tanh on 0:64) | [112:160) hk (tanh on 0:24) | [160:184) hv | [184:304) hrg (sigm)
__global__ __launch_bounds__(256) void k5_fuse(
    const float* __restrict__ hwa, const float* __restrict__ hk, const float* __restrict__ hv,
    const float* __restrict__ hrg,
    const float* __restrict__ dw2, const float* __restrict__ aaa_w2, const float* __restrict__ kkk_w2,
    const float* __restrict__ gate_w2, const float* __restrict__ ma_w2, const float* __restrict__ mk_w2,
    const float* __restrict__ mv_w2,
    const float* __restrict__ time_decay, const float* __restrict__ time_aaaaa,
    const float* __restrict__ misc_a, const float* __restrict__ misc_k, const float* __restrict__ misc_v,
    const float* __restrict__ v1,
    float* __restrict__ kbuf, float* __restrict__ vbuf, float* __restrict__ wexp,
    float* __restrict__ g, float* __restrict__ akv, float* __restrict__ bkv) {
  const int row0 = blockIdx.x*8, tid = threadIdx.x;
  const int lane = tid & 63;
  __shared__ float sall[8][304];
  __shared__ float sqh[8][Hdim];
  for (int idx=tid; idx<8*76; idx+=256){
    int rr = idx/76, q = (idx-rr*76)*4;
    float4 val;
    if (q < 112)      val = *(const float4*)&hwa[(size_t)(row0+rr)*112 + q];
    else if (q < 160) val = *(const float4*)&hk [(size_t)(row0+rr)*48  + (q-112)];
    else if (q < 184) val = *(const float4*)&hv [(size_t)(row0+rr)*24  + (q-160)];
    else              val = *(const float4*)&hrg[(size_t)(row0+rr)*120 + (q-184)];
    *(float4*)&sall[rr][q] = val;
  }
  __syncthreads();
  float kkv[3][8], av[3][8];
  #pragma unroll
  for (int it=0; it<3; it++){
    const int c = tid + it*256;
    const size_t ib = (size_t)row0*Cdim + c;
    float kraw[8];
    #pragma unroll
    for (int rr=0;rr<8;rr++) kraw[rr]=kbuf[ib + (size_t)rr*Cdim];
    float w8[8];
    { // decay (dw2, 64)
      float zd[8];
      float tdc = time_decay[c];
      #pragma unroll
      for (int rr=0;rr<8;rr++) zd[rr]=tdc;
      #pragma unroll 2
      for (int q4=0;q4<16;q4++){
        const int q = q4*4;
        float w0=dw2[(size_t)(q+0)*Cdim+c], w1=dw2[(size_t)(q+1)*Cdim+c],
              w2v=dw2[(size_t)(q+2)*Cdim+c], w3=dw2[(size_t)(q+3)*Cdim+c];
        #pragma unroll
        for (int rr=0;rr<8;rr++){
          float4 h4 = *(const float4*)&sall[rr][q];
          zd[rr] += h4.x*w0 + h4.y*w1 + h4.z*w2v + h4.w*w3;
        }
      }
      #pragma unroll
      for (int rr=0;rr<8;rr++){
        float w = -softplusf(-zd[rr]) - 0.5f;
        w8[rr]=w;
        wexp[ib + (size_t)rr*Cdim]=expf(-expf(w));
      }
    }
    { // a (aaa_w2) + kk (kkk_w2), both 24
      float za[8], zk[8];
      float aac = time_aaaaa[c];
      #pragma unroll
      for (int rr=0;rr<8;rr++){ za[rr]=aac; zk[rr]=0.f; }
      #pragma unroll 2
      for (int q4=0;q4<6;q4++){
        const int q = q4*4;
        float wa0=aaa_w2[(size_t)(q+0)*Cdim+c], wa1=aaa_w2[(size_t)(q+1)*Cdim+c],
              wa2=aaa_w2[(size_t)(q+2)*Cdim+c], wa3=aaa_w2[(size_t)(q+3)*Cdim+c];
        float wk0=kkk_w2[(size_t)(q+0)*Cdim+c], wk1=kkk_w2[(size_t)(q+1)*Cdim+c],
              wk2=kkk_w2[(size_t)(q+2)*Cdim+c], wk3=kkk_w2[(size_t)(q+3)*Cdim+c];
        #pragma unroll
        for (int rr=0;rr<8;rr++){
          float4 ha = *(const float4*)&sall[rr][64+q];
          float4 hkk = *(const float4*)&sall[rr][112+q];
          za[rr] += ha.x*wa0 + ha.y*wa1 + ha.z*wa2 + ha.w*wa3;
          zk[rr] += hkk.x*wk0 + hkk.y*wk1 + hkk.z*wk2 + hkk.w*wk3;
        }
      }
      #pragma unroll
      for (int rr=0;rr<8;rr++){
        av[it][rr]=sigm(za[rr]);
        kkv[it][rr]=kraw[rr]+zk[rr];
      }
    }
    { // ma, mk, mv (24 each) + elementwise k/v updates
      float zma[8], zmk[8], zmv[8];
      float mac=misc_a[c], mkc=misc_k[c], mvc=misc_v[c];
      #pragma unroll
      for (int rr=0;rr<8;rr++){ zma[rr]=mac; zmk[rr]=mkc; zmv[rr]=mvc; }
      #pragma unroll 2
      for (int q4=0;q4<6;q4++){
        const int q = q4*4;
        float w50=ma_w2[(size_t)(q+0)*Cdim+c], w51=ma_w2[(size_t)(q+1)*Cdim+c],
              w52=ma_w2[(size_t)(q+2)*Cdim+c], w53=ma_w2[(size_t)(q+3)*Cdim+c];
        float w60=mk_w2[(size_t)(q+0)*Cdim+c], w61=mk_w2[(size_t)(q+1)*Cdim+c],
              w62=mk_w2[(size_t)(q+2)*Cdim+c], w63=mk_w2[(size_t)(q+3)*Cdim+c];
        float w70=mv_w2[(size_t)(q+0)*Cdim+c], w71=mv_w2[(size_t)(q+1)*Cdim+c],
              w72=mv_w2[(size_t)(q+2)*Cdim+c], w73=mv_w2[(size_t)(q+3)*Cdim+c];
        #pragma unroll
        for (int rr=0;rr<8;rr++){
          float4 h5 = *(const float4*)&sall[rr][88+q];
          float4 h6 = *(const float4*)&sall[rr][136+q];
          float4 h7 = *(const float4*)&sall[rr][160+q];
          zma[rr] += h5.x*w50 + h5.y*w51 + h5.z*w52 + h5.w*w53;
          zmk[rr] += h6.x*w60 + h6.y*w61 + h6.z*w62 + h6.w*w63;
          zmv[rr] += h7.x*w70 + h7.y*w71 + h7.z*w72 + h7.w*w73;
        }
      }
      #pragma unroll
      for (int rr=0;rr<8;rr++){
        size_t i = ib + (size_t)rr*Cdim;
        float ma=sigm(zma[rr]), mk=sigm(zmk[rr]), mv=sigm(zmv[rr]);
        float v0=vbuf[i];
        vbuf[i]=v0+(v1[i]-v0)*mv;
        float k1=kraw[rr]*(ma + av[it][rr]*(1.f-ma));
        kbuf[i]=k1*expf(fminf(w8[rr]*mk,0.f));
      }
    }
    { // gate (sigm pre-applied, 120)
      float zg[8]={};
      #pragma unroll 2
      for (int q4=0;q4<30;q4++){
        const int q = q4*4;
        float w0=gate_w2[(size_t)(q+0)*Cdim+c], w1=gate_w2[(size_t)(q+1)*Cdim+c],
              w2v=gate_w2[(size_t)(q+2)*Cdim+c], w3=gate_w2[(size_t)(q+3)*Cdim+c];
        #pragma unroll
        for (int rr=0;rr<8;rr++){
          float4 h4 = *(const float4*)&sall[rr][184+q];
          zg[rr] += h4.x*w0 + h4.y*w1 + h4.z*w2v + h4.w*w3;
        }
      }
      #pragma unroll
      for (int rr=0;rr<8;rr++) g[ib + (size_t)rr*Cdim]=zg[rr];
    }
    // per-head sumsq of kk: lanes 0-31 / 32-63 each cover one full head
    #pragma unroll
    for (int rr=0;rr<8;rr++){
      float s = red32(kkv[it][rr]*kkv[it][rr]);
      if ((lane&31)==0) sqh[rr][c>>5] = s;
    }
  }
  __syncthreads();
  for (int idx=tid; idx<8*Hdim; idx+=256){
    int rr=idx/Hdim, hh=idx-rr*Hdim;
    sqh[rr][hh] = 1.f/fmaxf(sqrtf(sqh[rr][hh]),1e-12f);
  }
  __syncthreads();
  #pragma unroll
  for (int it=0; it<3; it++){
    const int c = tid + it*256;
    const size_t ib = (size_t)row0*Cdim + c;
    #pragma unroll
    for (int rr=0;rr<8;rr++){
      float kkn = kkv[it][rr]*sqh[rr][c>>5];
      akv[ib + (size_t)rr*Cdim]=-kkn;
      bkv[ib + (size_t)rr*Cdim]=kkn*av[it][rr];
    }
  }
}

// ---------------- K6: WKV7 (unchanged from round 4) ----------------
__global__ __launch_bounds__(64) void k6_wkv(const float* __restrict__ r, const float* __restrict__ wd,
    const float* __restrict__ k, const float* __restrict__ v,
    const float* __restrict__ a, const float* __restrict__ b2, float* __restrict__ y) {
  const int lane = threadIdx.x;
  const int head = blockIdx.x;
  const int bb = head / Hdim, hh = head - bb*Hdim;
  const int i0 = lane >> 2;
  const int jq = lane & 3;
  const int col = jq*8;
  __shared__ __align__(16) float sb[2][6][CH6][Ndim];
  const float* gptr[6] = {r, wd, k, v, a, b2};
  const size_t gbase = (size_t)bb*Tdim*Cdim + (size_t)hh*Ndim;
  float S0[8], S1[8];
  #pragma unroll
  for (int m=0;m<8;m++){ S0[m]=0.f; S1[m]=0.f; }
  const int tl = lane>>3, c4 = (lane&7)*4;

  auto STAGE = [&](int c, int buf){
    const size_t tb = (size_t)c*CH6;
    #pragma unroll
    for (int arr=0; arr<6; arr++){
      const float* gp = gptr[arr] + gbase;
      GLDS16(gp + (tb + tl)*Cdim + c4,     &sb[buf][arr][0][0]);
      GLDS16(gp + (tb + 8 + tl)*Cdim + c4, &sb[buf][arr][8][0]);
    }
  };

  STAGE(0, 0);
  asm volatile("s_waitcnt vmcnt(0)" ::: "memory");
  int cur = 0;
  const int NCH = Tdim/CH6;
  for (int c=0; c<NCH; ++c){
    if (c+1 < NCH) STAGE(c+1, cur^1);
    const size_t yb = gbase + (size_t)c*CH6*Cdim;
    #pragma unroll
    for (int t=0; t<CH6; t++){
      float avv[8], wv[8], kv[8], bv[8], rv[8];
      *(float4*)&avv[0]=*(const float4*)&sb[cur][4][t][col]; *(float4*)&avv[4]=*(const float4*)&sb[cur][4][t][col+4];
      *(float4*)&wv[0]=*(const float4*)&sb[cur][1][t][col]; *(float4*)&wv[4]=*(const float4*)&sb[cur][1][t][col+4];
      *(float4*)&kv[0]=*(const float4*)&sb[cur][2][t][col]; *(float4*)&kv[4]=*(const float4*)&sb[cur][2][t][col+4];
      *(float4*)&bv[0]=*(const float4*)&sb[cur][5][t][col]; *(float4*)&bv[4]=*(const float4*)&sb[cur][5][t][col+4];
      *(float4*)&rv[0]=*(const float4*)&sb[cur][0][t][col]; *(float4*)&rv[4]=*(const float4*)&sb[cur][0][t][col+4];
      const float vl0 = sb[cur][3][t][i0];
      const float vl1 = sb[cur][3][t][i0+16];
      float sa0=0.f, sa1=0.f;
      #pragma unroll
      for (int j=0;j<8;j++){ sa0 += S0[j]*avv[j]; sa1 += S1[j]*avv[j]; }
      sa0 = dpp_add<0xB1>(sa0); sa0 = dpp_add<0x4E>(sa0);
      sa1 = dpp_add<0xB1>(sa1); sa1 = dpp_add<0x4E>(sa1);
      float y0=0.f, y1=0.f;
      #pragma unroll
      for (int j=0;j<8;j++){
        S0[j] = S0[j]*wv[j] + (sa0*bv[j] + vl0*kv[j]);
        S1[j] = S1[j]*wv[j] + (sa1*bv[j] + vl1*kv[j]);
        y0 += S0[j]*rv[j];
        y1 += S1[j]*rv[j];
      }
      y0 = dpp_add<0xB1>(y0); y0 = dpp_add<0x4E>(y0);
      y1 = dpp_add<0xB1>(y1); y1 = dpp_add<0x4E>(y1);
      if (jq == 0){
        y[yb + (size_t)t*Cdim + i0]      = y0;
        y[yb + (size_t)t*Cdim + i0 + 16] = y1;
      }
    }
    asm volatile("s_waitcnt vmcnt(0)" ::: "memory");
    cur ^= 1;
  }
}

// ---------------- K7 v2: GroupNorm + bonus + gate, in-wave reductions, no barriers ----------------
__global__ __launch_bounds__(256) void k7_post(const float* __restrict__ y,
    const float* __restrict__ r, const float* __restrict__ kf, const float* __restrict__ v,
    const float* __restrict__ g, const float* __restrict__ faaaa,
    const float* __restrict__ lnw, const float* __restrict__ lnb,
    __hip_bfloat16* __restrict__ ygate) {
  const int row = blockIdx.x, tid = threadIdx.x;
  #pragma unroll
  for (int it=0; it<3; it++){
    const int c = tid + it*256;
    const size_t i = (size_t)row*Cdim + c;
    float yv = y[i];
    float bon = r[i]*kf[i]*faaaa[c];
    float s  = red32(yv);
    float ss = red32(yv*yv);
    float bn = red32(bon);
    float mu = s*(1.f/Ndim);
    float var = ss*(1.f/Ndim) - mu*mu;
    float rs = rsqrtf(var + 6.4e-5f);
    float yn = (yv-mu)*rs*lnw[c]+lnb[c];
    ygate[i]=__float2bfloat16((yn + bn*v[i])*g[i]);
  }
}

// ---------------- K9: v1 passthrough ----------------
__global__ void k9_copy(const float* __restrict__ src, float* __restrict__ dst){
  int idx = blockIdx.x*256 + threadIdx.x;
  if (idx < BTdim*Cdim) dst[idx]=src[idx];
}

extern "C" void kernel_launch(void* const* d_in, const int* in_sizes, int n_in,
                              void* d_out, int out_size, void* d_ws, size_t ws_size,
                              hipStream_t stream) {
  const float* x      = (const float*)d_in[0];
  const float* v1     = (const float*)d_in[1];
  const float* maa_x  = (const float*)d_in[2];
  const float* maa_rg = (const float*)d_in[3];
  const float* maa_wa = (const float*)d_in[4];
  const float* maa_k  = (const float*)d_in[5];
  const float* maa_v  = (const float*)d_in[6];
  const float* time_decay = (const float*)d_in[7];
  const float* faaaa  = (const float*)d_in[8];
  const float* aaaaa  = (const float*)d_in[9];
  const float* maa_w1 = (const float*)d_in[10];
  const float* maa_w2 = (const float*)d_in[11];
  const float* dw1    = (const float*)d_in[12];
  const float* dw2    = (const float*)d_in[13];
  const float* aaa_w1 = (const float*)d_in[14];
  const float* aaa_w2 = (const float*)d_in[15];
  const float* kkk_w1 = (const float*)d_in[16];
  const float* kkk_w2 = (const float*)d_in[17];
  const float* gate_w1= (const float*)d_in[18];
  const float* gate_w2= (const float*)d_in[19];
  const float* ma_w1  = (const float*)d_in[20];
  const float* ma_w2  = (const float*)d_in[21];
  const float* misc_a = (const float*)d_in[22];
  const float* mk_w1  = (const float*)d_in[23];
  const float* mk_w2  = (const float*)d_in[24];
  const float* misc_k = (const float*)d_in[25];
  const float* mv_w1  = (const float*)d_in[26];
  const float* mv_w2  = (const float*)d_in[27];
  const float* misc_v = (const float*)d_in[28];
  const float* Wr     = (const float*)d_in[29];
  const float* Wk     = (const float*)d_in[30];
  const float* Wv     = (const float*)d_in[31];
  const float* Wo     = (const float*)d_in[32];
  const float* lnw    = (const float*)d_in[33];
  const float* lnb    = (const float*)d_in[34];
  float* out = (float*)d_out;

  float* ws = (float*)d_ws;
  const size_t BTC = (size_t)BTdim*Cdim;
  float* ws0 = ws + 0*BTC;   // xx -> ybuf
  float* ws1 = ws + 1*BTC;   // xxx_bf -> {xrg_bf,xwa_bf} -> akv -> yg_bf
  float* ws2 = ws + 2*BTC;   // {xk_bf,xv_bf} -> bkv
  float* rb  = ws + 3*BTC;
  float* kb  = ws + 4*BTC;
  float* vb  = ws + 5*BTC;
  float* wexp= ws + 6*BTC;
  float* gb  = ws + 7*BTC;
  float* p   = ws + 8*BTC;
  float* tm  = p;               p += (size_t)BTdim*112;
  float* hwa = p;               p += (size_t)BTdim*112;
  float* hk  = p;               p += (size_t)BTdim*48;
  float* hv  = p;               p += (size_t)BTdim*24;
  float* hrg = p;               p += (size_t)BTdim*120;
  __hip_bfloat16* WtR = (__hip_bfloat16*)p;   // 4 x 589824 bf16
  __hip_bfloat16* WtK = WtR + 589824;
  __hip_bfloat16* WtV = WtK + 589824;
  __hip_bfloat16* WtO = WtV + 589824;
  __hip_bfloat16* PWwa = WtO + 589824;        // 5 x 98304 bf16
  __hip_bfloat16* PWk  = PWwa + 98304;
  __hip_bfloat16* PWv  = PWk  + 98304;
  __hip_bfloat16* PWrg = PWv  + 98304;
  __hip_bfloat16* PWmaa= PWrg + 98304;

  float* xx  = ws0;
  __hip_bfloat16* xxx_bf = (__hip_bfloat16*)ws1;
  __hip_bfloat16* xrg_bf = (__hip_bfloat16*)ws1;
  __hip_bfloat16* xwa_bf = xrg_bf + BTC;
  __hip_bfloat16* xk_bf  = (__hip_bfloat16*)ws2;
  __hip_bfloat16* xv_bf  = xk_bf + BTC;
  float* akv = ws1;
  float* bkv = ws2;
  float* ybuf = ws0;
  __hip_bfloat16* yg_bf = (__hip_bfloat16*)ws1;

  dim3 blk(256);
  kconvW<<<dim3(24,24,4), blk, 0, stream>>>(Wr,Wk,Wv,Wo, WtR,WtK,WtV,WtO);
  kprep<<<dim3((5*128*768+255)/256), blk, 0, stream>>>(dw1,aaa_w1,ma_w1,kkk_w1,mk_w1,mv_w1,gate_w1,maa_w1,
                                                       PWwa,PWk,PWv,PWrg,PWmaa);
  k1_shift<<<dim3((BTdim*Cdim+255)/256), blk, 0, stream>>>(x, maa_x, xx, xxx_bf);
  {
    G4 pt{};
    pt.A[0]=xxx_bf; pt.Bt[0]=PWmaa; pt.C[0]=tm; pt.N[0]=112; pt.act[0]=4;
    gemm_small<<<dim3(1,64,1), blk, 0, stream>>>(pt, Cdim);
  }
  k2_mix<<<dim3(BTdim/8), blk, 0, stream>>>(x, xx, tm, maa_w2, maa_rg, maa_wa, maa_k, maa_v,
                                            xrg_bf, xwa_bf, xk_bf, xv_bf);
  {
    G4 ph{};
    ph.A[0]=xwa_bf; ph.Bt[0]=PWwa; ph.C[0]=hwa; ph.N[0]=112; ph.act[0]=1;
    ph.A[1]=xk_bf;  ph.Bt[1]=PWk;  ph.C[1]=hk;  ph.N[1]=48;  ph.act[1]=2;
    ph.A[2]=xv_bf;  ph.Bt[2]=PWv;  ph.C[2]=hv;  ph.N[2]=24;  ph.act[2]=0;
    ph.A[3]=xrg_bf; ph.Bt[3]=PWrg; ph.C[3]=hrg; ph.N[3]=120; ph.act[3]=3;
    gemm_small<<<dim3(1,64,4), blk, 0, stream>>>(ph, Cdim);
  }
  gemm_mfma<<<dim3(6,64), blk, 0, stream>>>(xrg_bf, WtR, rb, BTdim, Cdim, Cdim);
  gemm_mfma<<<dim3(6,64), blk, 0, stream>>>(xk_bf,  WtK, kb, BTdim, Cdim, Cdim);
  gemm_mfma<<<dim3(6,64), blk, 0, stream>>>(xv_bf,  WtV, vb, BTdim, Cdim, Cdim);
  k5_fuse<<<dim3(BTdim/8), blk, 0, stream>>>(hwa,hk,hv,hrg,
      dw2,aaa_w2,kkk_w2,gate_w2,ma_w2,mk_w2,mv_w2,
      time_decay, aaaaa, misc_a, misc_k, misc_v, v1,
      kb, vb, wexp, gb, akv, bkv);
  k6_wkv<<<dim3(Bdim*Hdim), dim3(64), 0, stream>>>(rb, wexp, kb, vb, akv, bkv, ybuf);
  k7_post<<<dim3(BTdim), blk, 0, stream>>>(ybuf, rb, kb, vb, gb, faaaa, lnw, lnb, yg_bf);
  gemm_mfma<<<dim3(6,64), blk, 0, stream>>>(yg_bf, WtO, out, BTdim, Cdim, Cdim);
  k9_copy<<<dim3((BTdim*Cdim+255)/256), blk, 0, stream>>>(v1, out + BTC);
}

// Round 6
// 690.034 us; speedup vs baseline: 1.4795x; 1.4795x over previous
//
#include <hip/hip_runtime.h>
#include <hip/hip_bf16.h>
#include <math.h>

#define Bdim 8
#define Tdim 1024
#define Cdim 768
#define Hdim 24
#define Ndim 32
#define BTdim (Bdim*Tdim)
#define CH6 16

typedef __attribute__((ext_vector_type(8))) short bf16x8;
typedef __attribute__((ext_vector_type(4))) float f32x4;
typedef __hip_bfloat16 bf16;

__device__ __forceinline__ float sigm(float x){ return 1.f/(1.f+expf(-x)); }
__device__ __forceinline__ float softplusf(float x){ return fmaxf(x,0.f) + log1pf(expf(-fabsf(x))); }
__device__ __forceinline__ float bf2f(bf16 v){ return __bfloat162float(v); }
__device__ __forceinline__ float us2f(unsigned short s){ return __builtin_bit_cast(float, (unsigned)s<<16); }

template<int CTRL>
__device__ __forceinline__ float dpp_add(float x){
  int xi = __builtin_bit_cast(int, x);
  int yi = __builtin_amdgcn_mov_dpp(xi, CTRL, 0xF, 0xF, true);
  return x + __builtin_bit_cast(float, yi);
}
__device__ __forceinline__ float red32(float x){
  x = dpp_add<0xB1>(x);
  x = dpp_add<0x4E>(x);
  x = dpp_add<0x141>(x);
  x = dpp_add<0x140>(x);
  x += __shfl_xor(x, 16);
  return x;
}
__device__ __forceinline__ void cvt8(uint4 u, float* d){
  d[0]=__builtin_bit_cast(float, u.x<<16); d[1]=__builtin_bit_cast(float, u.x&0xFFFF0000u);
  d[2]=__builtin_bit_cast(float, u.y<<16); d[3]=__builtin_bit_cast(float, u.y&0xFFFF0000u);
  d[4]=__builtin_bit_cast(float, u.z<<16); d[5]=__builtin_bit_cast(float, u.z&0xFFFF0000u);
  d[6]=__builtin_bit_cast(float, u.w<<16); d[7]=__builtin_bit_cast(float, u.w&0xFFFF0000u);
}

#define GLDS16(gp, lp) __builtin_amdgcn_global_load_lds((const __attribute__((address_space(1))) void*)(gp), (__attribute__((address_space(3))) void*)(lp), 16, 0, 0)

// ---------------- K1: token shift ----------------
__global__ void k1_shift(const float* __restrict__ x, const float* __restrict__ maa_x,
                         float* __restrict__ xx, bf16* __restrict__ xxx) {
  int idx = blockIdx.x*256 + threadIdx.x;
  if (idx >= BTdim*Cdim) return;
  int c = idx % Cdim; int row = idx / Cdim; int t = row % Tdim;
  float xv = x[idx];
  float xp = (t==0) ? 0.f : x[idx - Cdim];
  float d = xp - xv;
  xx[idx] = d;
  xxx[idx] = __float2bfloat16(xv + d*maa_x[c]);
}

// ---------------- big weight convert + transpose ----------------
__global__ __launch_bounds__(256) void kconvW(const float* __restrict__ W0, const float* __restrict__ W1,
    const float* __restrict__ W2, const float* __restrict__ W3,
    bf16* __restrict__ T0, bf16* __restrict__ T1, bf16* __restrict__ T2, bf16* __restrict__ T3) {
  const float* Wsrc[4] = {W0,W1,W2,W3};
  bf16* Tdst[4] = {T0,T1,T2,T3};
  const float* W = Wsrc[blockIdx.z];
  bf16* T = Tdst[blockIdx.z];
  __shared__ float tile[32][33];
  int bx = blockIdx.x*32, by = blockIdx.y*32;
  int tx = threadIdx.x & 31, ty = threadIdx.x >> 5;
  #pragma unroll
  for (int q=0;q<32;q+=8) tile[ty+q][tx] = W[(size_t)(by+ty+q)*Cdim + bx+tx];
  __syncthreads();
  #pragma unroll
  for (int q=0;q<32;q+=8) T[(size_t)(bx+ty+q)*Cdim + by+tx] = __float2bfloat16(tile[tx][ty+q]);
}

// ---------------- pack stage-1 and stage-2 small weights (transposed bf16, zero-padded) ----------------
__global__ __launch_bounds__(256) void kprep(const float* __restrict__ dw1, const float* __restrict__ aaa_w1,
    const float* __restrict__ ma_w1, const float* __restrict__ kkk_w1, const float* __restrict__ mk_w1,
    const float* __restrict__ mv_w1, const float* __restrict__ gate_w1, const float* __restrict__ maa_w1,
    const float* __restrict__ dw2, const float* __restrict__ aaa_w2, const float* __restrict__ ma_w2,
    const float* __restrict__ kkk_w2, const float* __restrict__ mk_w2, const float* __restrict__ mv_w2,
    const float* __restrict__ gate_w2,
    bf16* __restrict__ PWwa, bf16* __restrict__ PWk, bf16* __restrict__ PWv,
    bf16* __restrict__ PWrg, bf16* __restrict__ PWmaa,
    bf16* __restrict__ W2wa, bf16* __restrict__ W2k, bf16* __restrict__ W2v, bf16* __restrict__ W2g){
  int idx = blockIdx.x*256 + threadIdx.x;
  if (idx < 491520) {
    int buf = idx / 98304, rem = idx - buf*98304;
    int n = rem / 768, kk = rem - n*768;
    float val = 0.f;
    bf16* dst;
    switch(buf){
      case 0: dst=PWwa; if(n<64) val=dw1[(size_t)kk*64+n]; else if(n<88) val=aaa_w1[(size_t)kk*24+(n-64)]; else if(n<112) val=ma_w1[(size_t)kk*24+(n-88)]; break;
      case 1: dst=PWk;  if(n<24) val=kkk_w1[(size_t)kk*24+n]; else if(n<48) val=mk_w1[(size_t)kk*24+(n-24)]; break;
      case 2: dst=PWv;  if(n<24) val=mv_w1[(size_t)kk*24+n]; break;
      case 3: dst=PWrg; if(n<120) val=gate_w1[(size_t)kk*120+n]; break;
      default: dst=PWmaa; if(n<112) val=maa_w1[(size_t)kk*112+n]; break;
    }
    dst[rem] = __float2bfloat16(val);
    return;
  }
  int i = idx - 491520;
  if (i < 294912){            // W2wa [2304][128]
    int n=i>>7, q=i&127, seg=n/768, c=n-seg*768;
    float val=0.f;
    if (seg==0){ if(q<64) val=dw2[(size_t)q*768+c]; }
    else if (seg==1){ if(q>=64&&q<88) val=aaa_w2[(size_t)(q-64)*768+c]; }
    else { if(q>=88&&q<112) val=ma_w2[(size_t)(q-88)*768+c]; }
    W2wa[i]=__float2bfloat16(val); return;
  }
  i -= 294912;
  if (i < 98304){             // W2k [1536][64]
    int n=i>>6, q=i&63, seg=n/768, c=n-seg*768;
    float val=0.f;
    if (seg==0){ if(q<24) val=kkk_w2[(size_t)q*768+c]; }
    else { if(q>=24&&q<48) val=mk_w2[(size_t)(q-24)*768+c]; }
    W2k[i]=__float2bfloat16(val); return;
  }
  i -= 98304;
  if (i < 24576){             // W2v [768][32]
    int c=i>>5, q=i&31;
    float val = (q<24) ? mv_w2[(size_t)q*768+c] : 0.f;
    W2v[i]=__float2bfloat16(val); return;
  }
  i -= 24576;
  if (i < 98304){             // W2g [768][128]
    int c=i>>7, q=i&127;
    float val = (q<120) ? gate_w2[(size_t)q*768+c] : 0.f;
    W2g[i]=__float2bfloat16(val);
  }
}

// ---------------- big bf16 MFMA GEMM, templated output dtype ----------------
template<typename OutT>
__global__ __launch_bounds__(256) void gemm_mfma(const bf16* __restrict__ A,
    const bf16* __restrict__ Bt, OutT* __restrict__ C, int M, int N, int K) {
  __shared__ unsigned short As[128*32];
  __shared__ unsigned short Bs[128*32];
  const int bm = blockIdx.y*128, bn = blockIdx.x*128;
  const int tid = threadIdx.x, lane = tid&63, w = tid>>6;
  const int wr = w>>1, wc = w&1;
  const int lr = lane&15, kg = lane>>4;
  f32x4 zero = {0.f,0.f,0.f,0.f};
  f32x4 acc[4][4];
  #pragma unroll
  for (int m=0;m<4;m++)
    #pragma unroll
    for (int n=0;n<4;n++) acc[m][n]=zero;
  const size_t rowA = (size_t)(bm + w*32 + (lane>>2))*K + (lane&3)*8;
  const size_t rowB = (size_t)(bn + w*32 + (lane>>2))*K + (lane&3)*8;
  unsigned short* lA = As + w*32*32;
  unsigned short* lB = Bs + w*32*32;
  for (int k0=0; k0<K; k0+=32){
    GLDS16(A + rowA + k0,                 lA);
    GLDS16(A + rowA + k0 + (size_t)16*K,  lA + 512);
    GLDS16(Bt + rowB + k0,                lB);
    GLDS16(Bt + rowB + k0 + (size_t)16*K, lB + 512);
    __syncthreads();
    bf16x8 af[4], bfr[4];
    #pragma unroll
    for (int m=0;m<4;m++) af[m]  = *(const bf16x8*)(void*)(As + (wr*64+m*16+lr)*32 + kg*8);
    #pragma unroll
    for (int n=0;n<4;n++) bfr[n] = *(const bf16x8*)(void*)(Bs + (wc*64+n*16+lr)*32 + kg*8);
    #pragma unroll
    for (int m=0;m<4;m++)
      #pragma unroll
      for (int n=0;n<4;n++)
        acc[m][n] = __builtin_amdgcn_mfma_f32_16x16x32_bf16(af[m], bfr[n], acc[m][n], 0,0,0);
    __syncthreads();
  }
  #pragma unroll
  for (int m=0;m<4;m++)
    #pragma unroll
    for (int n=0;n<4;n++){
      size_t r0 = (size_t)(bm + wr*64 + m*16 + kg*4);
      int cc = bn + wc*64 + n*16 + lr;
      #pragma unroll
      for (int q=0;q<4;q++){
        float val = acc[m][n][q];
        if constexpr (sizeof(OutT)==2) C[(r0+q)*N + cc] = __float2bfloat16(val);
        else                           C[(r0+q)*N + cc] = val;
      }
    }
}

// ---------------- gemm_tm: f32 out, N=112, tanh ----------------
__global__ __launch_bounds__(256) void gemm_tm(const bf16* __restrict__ A,
    const bf16* __restrict__ Bt, float* __restrict__ C, int K) {
  __shared__ unsigned short As[128*32];
  __shared__ unsigned short Bs[128*32];
  const int bm = blockIdx.y*128;
  const int tid = threadIdx.x, lane = tid&63, w = tid>>6;
  const int wr = w>>1, wc = w&1;
  const int lr = lane&15, kg = lane>>4;
  f32x4 zero = {0.f,0.f,0.f,0.f};
  f32x4 acc[4][4];
  #pragma unroll
  for (int m=0;m<4;m++)
    #pragma unroll
    for (int n=0;n<4;n++) acc[m][n]=zero;
  const size_t rowA = (size_t)(bm + w*32 + (lane>>2))*K + (lane&3)*8;
  const size_t rowB = (size_t)(w*32 + (lane>>2))*K + (lane&3)*8;
  unsigned short* lA = As + w*32*32;
  unsigned short* lB = Bs + w*32*32;
  for (int k0=0; k0<K; k0+=32){
    GLDS16(A + rowA + k0,                 lA);
    GLDS16(A + rowA + k0 + (size_t)16*K,  lA + 512);
    GLDS16(Bt + rowB + k0,                lB);
    GLDS16(Bt + rowB + k0 + (size_t)16*K, lB + 512);
    __syncthreads();
    bf16x8 af[4], bfr[4];
    #pragma unroll
    for (int m=0;m<4;m++) af[m]  = *(const bf16x8*)(void*)(As + (wr*64+m*16+lr)*32 + kg*8);
    #pragma unroll
    for (int n=0;n<4;n++) bfr[n] = *(const bf16x8*)(void*)(Bs + (wc*64+n*16+lr)*32 + kg*8);
    #pragma unroll
    for (int m=0;m<4;m++)
      #pragma unroll
      for (int n=0;n<4;n++)
        acc[m][n] = __builtin_amdgcn_mfma_f32_16x16x32_bf16(af[m], bfr[n], acc[m][n], 0,0,0);
    __syncthreads();
  }
  #pragma unroll
  for (int m=0;m<4;m++)
    #pragma unroll
    for (int n=0;n<4;n++){
      size_t r0 = (size_t)(bm + wr*64 + m*16 + kg*4);
      int cc = wc*64 + n*16 + lr;
      if (cc < 112){
        #pragma unroll
        for (int q=0;q<4;q++)
          C[(r0+q)*112 + cc] = tanhf(acc[m][n][q]);
      }
    }
}

// ---------------- stage-1 batched small GEMM -> bf16 padded, per-z activation ----------------
// act: 0 none; 1 tanh cols<64; 2 tanh cols<24; 3 sigm all
struct S1P {
  const bf16* A[4];
  const bf16* Bt[4];
  bf16* C[4];
  int Ntrue[4];
  int Nalloc[4];
  int act[4];
};
__global__ __launch_bounds__(256) void gemm_s1(S1P p, int K) {
  const int z = blockIdx.z;
  const bf16* __restrict__ A  = p.A[z];
  const bf16* __restrict__ Bt = p.Bt[z];
  bf16* __restrict__ C = p.C[z];
  const int Ntrue = p.Ntrue[z], Nalloc = p.Nalloc[z], act = p.act[z];
  __shared__ unsigned short As[128*32];
  __shared__ unsigned short Bs[128*32];
  const int bm = blockIdx.y*128;
  const int tid = threadIdx.x, lane = tid&63, w = tid>>6;
  const int wr = w>>1, wc = w&1;
  const int lr = lane&15, kg = lane>>4;
  f32x4 zero = {0.f,0.f,0.f,0.f};
  f32x4 acc[4][4];
  #pragma unroll
  for (int m=0;m<4;m++)
    #pragma unroll
    for (int n=0;n<4;n++) acc[m][n]=zero;
  const size_t rowA = (size_t)(bm + w*32 + (lane>>2))*K + (lane&3)*8;
  const size_t rowB = (size_t)(w*32 + (lane>>2))*K + (lane&3)*8;
  unsigned short* lA = As + w*32*32;
  unsigned short* lB = Bs + w*32*32;
  for (int k0=0; k0<K; k0+=32){
    GLDS16(A + rowA + k0,                 lA);
    GLDS16(A + rowA + k0 + (size_t)16*K,  lA + 512);
    GLDS16(Bt + rowB + k0,                lB);
    GLDS16(Bt + rowB + k0 + (size_t)16*K, lB + 512);
    __syncthreads();
    bf16x8 af[4], bfr[4];
    #pragma unroll
    for (int m=0;m<4;m++) af[m]  = *(const bf16x8*)(void*)(As + (wr*64+m*16+lr)*32 + kg*8);
    #pragma unroll
    for (int n=0;n<4;n++) bfr[n] = *(const bf16x8*)(void*)(Bs + (wc*64+n*16+lr)*32 + kg*8);
    #pragma unroll
    for (int m=0;m<4;m++)
      #pragma unroll
      for (int n=0;n<4;n++)
        acc[m][n] = __builtin_amdgcn_mfma_f32_16x16x32_bf16(af[m], bfr[n], acc[m][n], 0,0,0);
    __syncthreads();
  }
  #pragma unroll
  for (int m=0;m<4;m++)
    #pragma unroll
    for (int n=0;n<4;n++){
      size_t r0 = (size_t)(bm + wr*64 + m*16 + kg*4);
      int cc = wc*64 + n*16 + lr;
      if (cc < Nalloc){
        #pragma unroll
        for (int q=0;q<4;q++){
          float val = acc[m][n][q];
          if      (act==1){ if (cc<64) val = tanhf(val); }
          else if (act==2){ if (cc<24) val = tanhf(val); }
          else if (act==3){ val = sigm(val); }
          if (cc >= Ntrue) val = 0.f;
          C[(r0+q)*Nalloc + cc] = __float2bfloat16(val);
        }
      }
    }
}

// ---------------- stage-2 batched GEMM: z = h @ W2 -> bf16 ----------------
struct Z4 {
  const bf16* A[4];
  const bf16* Bt[4];
  bf16* C[4];
  int N[4];
  int K[4];
};
__global__ __launch_bounds__(256) void gemm_z(Z4 p) {
  const int z = blockIdx.z;
  const int N = p.N[z], K = p.K[z];
  const int bn = blockIdx.x*128;
  if (bn >= N) return;
  const bf16* __restrict__ A  = p.A[z];
  const bf16* __restrict__ Bt = p.Bt[z];
  bf16* __restrict__ C = p.C[z];
  __shared__ unsigned short As[128*32];
  __shared__ unsigned short Bs[128*32];
  const int bm = blockIdx.y*128;
  const int tid = threadIdx.x, lane = tid&63, w = tid>>6;
  const int wr = w>>1, wc = w&1;
  const int lr = lane&15, kg = lane>>4;
  f32x4 zero = {0.f,0.f,0.f,0.f};
  f32x4 acc[4][4];
  #pragma unroll
  for (int m=0;m<4;m++)
    #pragma unroll
    for (int n=0;n<4;n++) acc[m][n]=zero;
  const size_t rowA = (size_t)(bm + w*32 + (lane>>2))*K + (lane&3)*8;
  const size_t rowB = (size_t)(bn + w*32 + (lane>>2))*K + (lane&3)*8;
  unsigned short* lA = As + w*32*32;
  unsigned short* lB = Bs + w*32*32;
  for (int k0=0; k0<K; k0+=32){
    GLDS16(A + rowA + k0,                 lA);
    GLDS16(A + rowA + k0 + (size_t)16*K,  lA + 512);
    GLDS16(Bt + rowB + k0,                lB);
    GLDS16(Bt + rowB + k0 + (size_t)16*K, lB + 512);
    __syncthreads();
    bf16x8 af[4], bfr[4];
    #pragma unroll
    for (int m=0;m<4;m++) af[m]  = *(const bf16x8*)(void*)(As + (wr*64+m*16+lr)*32 + kg*8);
    #pragma unroll
    for (int n=0;n<4;n++) bfr[n] = *(const bf16x8*)(void*)(Bs + (wc*64+n*16+lr)*32 + kg*8);
    #pragma unroll
    for (int m=0;m<4;m++)
      #pragma unroll
      for (int n=0;n<4;n++)
        acc[m][n] = __builtin_amdgcn_mfma_f32_16x16x32_bf16(af[m], bfr[n], acc[m][n], 0,0,0);
    __syncthreads();
  }
  #pragma unroll
  for (int m=0;m<4;m++)
    #pragma unroll
    for (int n=0;n<4;n++){
      size_t r0 = (size_t)(bm + wr*64 + m*16 + kg*4);
      int cc = bn + wc*64 + n*16 + lr;
      #pragma unroll
      for (int q=0;q<4;q++)
        C[(r0+q)*N + cc] = __float2bfloat16(acc[m][n][q]);
    }
}

// ---------------- K2b: mix, 8 rows per block (round-4 form; tm pre-tanh'd) ----------------
__global__ __launch_bounds__(256) void k2_mix(const float* __restrict__ x, const float* __restrict__ xx,
    const float* __restrict__ tm, const float* __restrict__ w2,
    const float* __restrict__ mrg, const float* __restrict__ mwa,
    const float* __restrict__ mk_, const float* __restrict__ mv_,
    bf16* __restrict__ xrg, bf16* __restrict__ xwa, bf16* __restrict__ xk, bf16* __restrict__ xv) {
  const int row0 = blockIdx.x*8, tid = threadIdx.x;
  __shared__ float stm[8][112];
  for (int idx=tid; idx<8*112; idx+=256){
    int rr=idx/112, q=idx-rr*112;
    stm[rr][q]=tm[(size_t)(row0+rr)*112+q];
  }
  __syncthreads();
  for (int c=tid;c<Cdim;c+=256){
    float x8[8], d8[8];
    #pragma unroll
    for (int rr=0;rr<8;rr++){
      size_t i=(size_t)(row0+rr)*Cdim+c;
      x8[rr]=x[i]; d8[rr]=xx[i];
    }
    float mrgc=mrg[c], mwac=mwa[c], mkc=mk_[c], mvc=mv_[c];
    float m0[8]={},m1[8]={},m2[8]={},m3[8]={};
    #pragma unroll 4
    for (int d=0; d<28; d++){
      float w0=w2[(size_t)(d)*Cdim + c];
      float w1=w2[(size_t)(28+d)*Cdim + c];
      float w2v=w2[(size_t)(56+d)*Cdim + c];
      float w3=w2[(size_t)(84+d)*Cdim + c];
      #pragma unroll
      for (int rr=0;rr<8;rr++){
        m0[rr]+=stm[rr][d]*w0; m1[rr]+=stm[rr][28+d]*w1;
        m2[rr]+=stm[rr][56+d]*w2v; m3[rr]+=stm[rr][84+d]*w3;
      }
    }
    #pragma unroll
    for (int rr=0;rr<8;rr++){
      size_t i=(size_t)(row0+rr)*Cdim+c;
      xrg[i]=__float2bfloat16(x8[rr] + d8[rr]*(mrgc+m0[rr]));
      xwa[i]=__float2bfloat16(x8[rr] + d8[rr]*(mwac+m1[rr]));
      xk[i] =__float2bfloat16(x8[rr] + d8[rr]*(mkc+m2[rr]));
      xv[i] =__float2bfloat16(x8[rr] + d8[rr]*(mvc+m3[rr]));
    }
  }
}

// ---------------- K5 v3: pure elementwise + in-wave head norm ----------------
__global__ __launch_bounds__(256) void k5_fuse(
    const bf16* __restrict__ zwa, const bf16* __restrict__ zk, const bf16* __restrict__ zv,
    const float* __restrict__ td, const float* __restrict__ aaaaa,
    const float* __restrict__ misc_a, const float* __restrict__ misc_k, const float* __restrict__ misc_v,
    const float* __restrict__ v1,
    float* __restrict__ kbuf, float* __restrict__ vbuf, float* __restrict__ wexp,
    bf16* __restrict__ kb_bf, bf16* __restrict__ vb_bf,
    bf16* __restrict__ akv, bf16* __restrict__ bkv) {
  const int row = blockIdx.x, tid = threadIdx.x;
  float kraw[3], v0[3], v1v[3];
  #pragma unroll
  for (int it=0;it<3;it++){
    size_t i=(size_t)row*Cdim + tid + it*256;
    kraw[it]=kbuf[i]; v0[it]=vbuf[i]; v1v[it]=v1[i];
  }
  __syncthreads();   // all f32 reads of kbuf/vbuf done before bf16 overlay writes
  #pragma unroll
  for (int it=0;it<3;it++){
    const int c = tid + it*256;
    const size_t i=(size_t)row*Cdim+c;
    float zd = bf2f(zwa[(size_t)row*2304 + c]);
    float za = bf2f(zwa[(size_t)row*2304 + 768 + c]);
    float zma= bf2f(zwa[(size_t)row*2304 + 1536 + c]);
    float zkk= bf2f(zk[(size_t)row*1536 + c]);
    float zmk= bf2f(zk[(size_t)row*1536 + 768 + c]);
    float zmv= bf2f(zv[i]);
    float w = -softplusf(-(td[c]+zd)) - 0.5f;
    wexp[i] = expf(-expf(w));
    float a  = sigm(aaaaa[c]+za);
    float ma = sigm(misc_a[c]+zma);
    float mk = sigm(misc_k[c]+zmk);
    float mv = sigm(misc_v[c]+zmv);
    vb_bf[i] = __float2bfloat16(v0[it] + (v1v[it]-v0[it])*mv);
    float kf = kraw[it]*(ma + a*(1.f-ma))*expf(fminf(w*mk,0.f));
    kb_bf[i] = __float2bfloat16(kf);
    float kk = kraw[it] + zkk;
    float ss = red32(kk*kk);
    float kkn = kk * (1.f/fmaxf(sqrtf(ss),1e-12f));
    akv[i] = __float2bfloat16(-kkn);
    bkv[i] = __float2bfloat16(kkn*a);
  }
}

// ---------------- K6 v5: bf16 streams (w f32), register software pipeline ----------------
__global__ __launch_bounds__(64) void k6_wkv(const unsigned short* __restrict__ r, const float* __restrict__ wd,
    const unsigned short* __restrict__ k, const unsigned short* __restrict__ v,
    const unsigned short* __restrict__ a, const unsigned short* __restrict__ b2, float* __restrict__ y) {
  const int lane = threadIdx.x;
  const int head = blockIdx.x;
  const int bb = head / Hdim, hh = head - bb*Hdim;
  const int i0 = lane >> 2;
  const int jq = lane & 3;
  const int col = jq*8;
  __shared__ __align__(16) float swd[2][CH6][Ndim];                 // 4 KB
  __shared__ __align__(16) unsigned short sbf[2][4][CH6][Ndim];     // r,k,a,b : 8 KB
  __shared__ __align__(16) unsigned short sv[2][CH6][Ndim];         // 2 KB
  const unsigned short* gb16[5] = {r, k, a, b2, v};
  const size_t gbase = (size_t)bb*Tdim*Cdim + (size_t)hh*Ndim;
  float S0[8], S1[8];
  #pragma unroll
  for (int m=0;m<8;m++){ S0[m]=0.f; S1[m]=0.f; }

  auto STAGE = [&](int c, int buf){
    const size_t tb = (size_t)c*CH6;
    GLDS16(wd + gbase + (tb +   (lane>>3))*Cdim + (lane&7)*4, &swd[buf][0][0]);
    GLDS16(wd + gbase + (tb + 8+(lane>>3))*Cdim + (lane&7)*4, &swd[buf][8][0]);
    #pragma unroll
    for (int arr=0; arr<4; arr++)
      GLDS16(gb16[arr] + gbase + (tb + (lane>>2))*Cdim + (lane&3)*8, &sbf[buf][arr][0][0]);
    GLDS16(gb16[4] + gbase + (tb + (lane>>2))*Cdim + (lane&3)*8, &sv[buf][0][0]);
  };

  // next-step raw registers
  uint4 nr, nk, na, nb; float4 nw0, nw1; unsigned short nv0, nv1;
  auto LOADT = [&](int buf, int t){
    nr  = *(const uint4*)&sbf[buf][0][t][col];
    nk  = *(const uint4*)&sbf[buf][1][t][col];
    na  = *(const uint4*)&sbf[buf][2][t][col];
    nb  = *(const uint4*)&sbf[buf][3][t][col];
    nw0 = *(const float4*)&swd[buf][t][col];
    nw1 = *(const float4*)&swd[buf][t][col+4];
    nv0 = sv[buf][t][i0];
    nv1 = sv[buf][t][i0+16];
  };

  STAGE(0, 0);
  asm volatile("s_waitcnt vmcnt(0)" ::: "memory");
  LOADT(0, 0);
  int buf = 0;
  const int NCH = Tdim/CH6;
  for (int c=0; c<NCH; ++c){
    if (c+1 < NCH) STAGE(c+1, buf^1);
    const size_t yb = gbase + (size_t)c*CH6*Cdim;
    #pragma unroll
    for (int t=0; t<CH6; t++){
      uint4 cr=nr, ck=nk, ca=na, cb=nb;
      float4 cw0=nw0, cw1=nw1;
      unsigned short cv0=nv0, cv1=nv1;
      if (t < CH6-1) LOADT(buf, t+1);       // prefetch next step (raw)
      float av[8]; cvt8(ca, av);
      float sa0=0.f, sa1=0.f;
      #pragma unroll
      for (int j=0;j<8;j++){ sa0 += S0[j]*av[j]; sa1 += S1[j]*av[j]; }
      sa0 = dpp_add<0xB1>(sa0); sa0 = dpp_add<0x4E>(sa0);
      sa1 = dpp_add<0xB1>(sa1); sa1 = dpp_add<0x4E>(sa1);
      float wv[8] = {cw0.x,cw0.y,cw0.z,cw0.w,cw1.x,cw1.y,cw1.z,cw1.w};
      float kv[8]; cvt8(ck, kv);
      float bv[8]; cvt8(cb, bv);
      float rv[8]; cvt8(cr, rv);
      const float vl0 = us2f(cv0);
      const float vl1 = us2f(cv1);
      float y0=0.f, y1=0.f;
      #pragma unroll
      for (int j=0;j<8;j++){
        S0[j] = S0[j]*wv[j] + (sa0*bv[j] + vl0*kv[j]);
        S1[j] = S1[j]*wv[j] + (sa1*bv[j] + vl1*kv[j]);
        y0 += S0[j]*rv[j];
        y1 += S1[j]*rv[j];
      }
      y0 = dpp_add<0xB1>(y0); y0 = dpp_add<0x4E>(y0);
      y1 = dpp_add<0xB1>(y1); y1 = dpp_add<0x4E>(y1);
      if (jq == 0){
        y[yb + (size_t)t*Cdim + i0]      = y0;
        y[yb + (size_t)t*Cdim + i0 + 16] = y1;
      }
      if (t == CH6-1 && c+1 < NCH){
        asm volatile("s_waitcnt vmcnt(0)" ::: "memory");
        LOADT(buf^1, 0);                    // first step of next chunk
      }
    }
    buf ^= 1;
  }
}

// ---------------- K7 v3: GroupNorm + bonus + gate (bf16 inputs) ----------------
__global__ __launch_bounds__(256) void k7_post(const float* __restrict__ y,
    const bf16* __restrict__ r, const bf16* __restrict__ kf, const bf16* __restrict__ v,
    const bf16* __restrict__ g, const float* __restrict__ faaaa,
    const float* __restrict__ lnw, const float* __restrict__ lnb,
    bf16* __restrict__ ygate) {
  const int row = blockIdx.x, tid = threadIdx.x;
  #pragma unroll
  for (int it=0; it<3; it++){
    const int c = tid + it*256;
    const size_t i = (size_t)row*Cdim + c;
    float yv = y[i];
    float bon = bf2f(r[i])*bf2f(kf[i])*faaaa[c];
    float s  = red32(yv);
    float ss = red32(yv*yv);
    float bn = red32(bon);
    float mu = s*(1.f/Ndim);
    float var = ss*(1.f/Ndim) - mu*mu;
    float rs = rsqrtf(var + 6.4e-5f);
    float yn = (yv-mu)*rs*lnw[c]+lnb[c];
    ygate[i]=__float2bfloat16((yn + bn*bf2f(v[i]))*bf2f(g[i]));
  }
}

// ---------------- K9: v1 passthrough ----------------
__global__ void k9_copy(const float* __restrict__ src, float* __restrict__ dst){
  int idx = blockIdx.x*256 + threadIdx.x;
  if (idx < BTdim*Cdim) dst[idx]=src[idx];
}

extern "C" void kernel_launch(void* const* d_in, const int* in_sizes, int n_in,
                              void* d_out, int out_size, void* d_ws, size_t ws_size,
                              hipStream_t stream) {
  const float* x      = (const float*)d_in[0];
  const float* v1     = (const float*)d_in[1];
  const float* maa_x  = (const float*)d_in[2];
  const float* maa_rg = (const float*)d_in[3];
  const float* maa_wa = (const float*)d_in[4];
  const float* maa_k  = (const float*)d_in[5];
  const float* maa_v  = (const float*)d_in[6];
  const float* time_decay = (const float*)d_in[7];
  const float* faaaa  = (const float*)d_in[8];
  const float* aaaaa  = (const float*)d_in[9];
  const float* maa_w1 = (const float*)d_in[10];
  const float* maa_w2 = (const float*)d_in[11];
  const float* dw1    = (const float*)d_in[12];
  const float* dw2    = (const float*)d_in[13];
  const float* aaa_w1 = (const float*)d_in[14];
  const float* aaa_w2 = (const float*)d_in[15];
  const float* kkk_w1 = (const float*)d_in[16];
  const float* kkk_w2 = (const float*)d_in[17];
  const float* gate_w1= (const float*)d_in[18];
  const float* gate_w2= (const float*)d_in[19];
  const float* ma_w1  = (const float*)d_in[20];
  const float* ma_w2  = (const float*)d_in[21];
  const float* misc_a = (const float*)d_in[22];
  const float* mk_w1  = (const float*)d_in[23];
  const float* mk_w2  = (const float*)d_in[24];
  const float* misc_k = (const float*)d_in[25];
  const float* mv_w1  = (const float*)d_in[26];
  const float* mv_w2  = (const float*)d_in[27];
  const float* misc_v = (const float*)d_in[28];
  const float* Wr     = (const float*)d_in[29];
  const float* Wk     = (const float*)d_in[30];
  const float* Wv     = (const float*)d_in[31];
  const float* Wo     = (const float*)d_in[32];
  const float* lnw    = (const float*)d_in[33];
  const float* lnb    = (const float*)d_in[34];
  float* out = (float*)d_out;

  float* ws = (float*)d_ws;
  const size_t BTC = (size_t)BTdim*Cdim;   // 6291456
  const size_t HB  = BTC/2;                // 3145728
  // slots (f32 units): S1@0(2HB) S2@2(2) S3@4(2) S4@6(3) S5@9(2) S6@11(1) S7@12(1) S8@13(1) S9@14(1) S10@15(2) S11@17(1) W@18
  float* xx   = ws;                float* wexp = ws;
  float* kb   = ws + 2*HB;         bf16* kb_bf = (bf16*)kb;
  float* vb   = ws + 4*HB;         bf16* vb_bf = (bf16*)vb;
  bf16* xrg_bf = (bf16*)(ws + 6*HB);
  bf16* xwa_bf = xrg_bf + BTC;
  bf16* zwa_bf = (bf16*)(ws + 6*HB);
  bf16* xk_bf  = (bf16*)(ws + 9*HB);
  bf16* xv_bf  = xk_bf + BTC;
  bf16* zk_bf  = (bf16*)(ws + 9*HB);
  bf16* xxx_bf = (bf16*)(ws + 11*HB);
  bf16* zv_bf  = (bf16*)(ws + 11*HB);
  float* tm    = ws + 12*HB;
  bf16* zg_bf  = (bf16*)(ws + 12*HB);
  bf16* hwa_bf = (bf16*)(ws + 13*HB);
  bf16* hk_bf  = hwa_bf + (size_t)BTdim*128;
  bf16* hv_bf  = hk_bf  + (size_t)BTdim*64;
  bf16* hrg_bf = hv_bf  + (size_t)BTdim*32;
  bf16* akv_bf = (bf16*)(ws + 13*HB);
  bf16* bkv_bf = (bf16*)(ws + 14*HB);
  bf16* yg_bf  = (bf16*)(ws + 14*HB);
  float* ybuf  = ws + 15*HB;
  bf16* rb_bf  = (bf16*)(ws + 17*HB);
  bf16* Wbase  = (bf16*)(ws + 18*HB);
  bf16* WtR = Wbase;
  bf16* WtK = WtR + 589824;
  bf16* WtV = WtK + 589824;
  bf16* WtO = WtV + 589824;
  bf16* PWwa = WtO + 589824;
  bf16* PWk  = PWwa + 98304;
  bf16* PWv  = PWk  + 98304;
  bf16* PWrg = PWv  + 98304;
  bf16* PWmaa= PWrg + 98304;
  bf16* W2wa = PWmaa + 98304;
  bf16* W2k  = W2wa + 294912;
  bf16* W2v  = W2k  + 98304;
  bf16* W2g  = W2v  + 24576;

  dim3 blk(256);
  kconvW<<<dim3(24,24,4), blk, 0, stream>>>(Wr,Wk,Wv,Wo, WtR,WtK,WtV,WtO);
  kprep<<<dim3(3936), blk, 0, stream>>>(dw1,aaa_w1,ma_w1,kkk_w1,mk_w1,mv_w1,gate_w1,maa_w1,
                                        dw2,aaa_w2,ma_w2,kkk_w2,mk_w2,mv_w2,gate_w2,
                                        PWwa,PWk,PWv,PWrg,PWmaa, W2wa,W2k,W2v,W2g);
  k1_shift<<<dim3((BTdim*Cdim+255)/256), blk, 0, stream>>>(x, maa_x, xx, xxx_bf);
  gemm_tm<<<dim3(1,64), blk, 0, stream>>>(xxx_bf, PWmaa, tm, Cdim);
  k2_mix<<<dim3(BTdim/8), blk, 0, stream>>>(x, xx, tm, maa_w2, maa_rg, maa_wa, maa_k, maa_v,
                                            xrg_bf, xwa_bf, xk_bf, xv_bf);
  {
    S1P p{};
    p.A[0]=xwa_bf; p.Bt[0]=PWwa; p.C[0]=hwa_bf; p.Ntrue[0]=112; p.Nalloc[0]=128; p.act[0]=1;
    p.A[1]=xk_bf;  p.Bt[1]=PWk;  p.C[1]=hk_bf;  p.Ntrue[1]=48;  p.Nalloc[1]=64;  p.act[1]=2;
    p.A[2]=xv_bf;  p.Bt[2]=PWv;  p.C[2]=hv_bf;  p.Ntrue[2]=24;  p.Nalloc[2]=32;  p.act[2]=0;
    p.A[3]=xrg_bf; p.Bt[3]=PWrg; p.C[3]=hrg_bf; p.Ntrue[3]=120; p.Nalloc[3]=128; p.act[3]=3;
    gemm_s1<<<dim3(1,64,4), blk, 0, stream>>>(p, Cdim);
  }
  gemm_mfma<bf16> <<<dim3(6,64), blk, 0, stream>>>(xrg_bf, WtR, rb_bf, BTdim, Cdim, Cdim);
  gemm_mfma<float><<<dim3(6,64), blk, 0, stream>>>(xk_bf,  WtK, kb,    BTdim, Cdim, Cdim);
  gemm_mfma<float><<<dim3(6,64), blk, 0, stream>>>(xv_bf,  WtV, vb,    BTdim, Cdim, Cdim);
  {
    Z4 p{};
    p.A[0]=hwa_bf; p.Bt[0]=W2wa; p.C[0]=zwa_bf; p.N[0]=2304; p.K[0]=128;
    p.A[1]=hk_bf;  p.Bt[1]=W2k;  p.C[1]=zk_bf;  p.N[1]=1536; p.K[1]=64;
    p.A[2]=hv_bf;  p.Bt[2]=W2v;  p.C[2]=zv_bf;  p.N[2]=768;  p.K[2]=32;
    p.A[3]=hrg_bf; p.Bt[3]=W2g;  p.C[3]=zg_bf;  p.N[3]=768;  p.K[3]=128;
    gemm_z<<<dim3(18,64,4), blk, 0, stream>>>(p);
  }
  k5_fuse<<<dim3(BTdim), blk, 0, stream>>>(zwa_bf, zk_bf, zv_bf,
      time_decay, aaaaa, misc_a, misc_k, misc_v, v1,
      kb, vb, wexp, kb_bf, vb_bf, akv_bf, bkv_bf);
  k6_wkv<<<dim3(Bdim*Hdim), dim3(64), 0, stream>>>((const unsigned short*)rb_bf, wexp,
      (const unsigned short*)kb_bf, (const unsigned short*)vb_bf,
      (const unsigned short*)akv_bf, (const unsigned short*)bkv_bf, ybuf);
  k7_post<<<dim3(BTdim), blk, 0, stream>>>(ybuf, rb_bf, kb_bf, vb_bf, zg_bf, faaaa, lnw, lnb, yg_bf);
  gemm_mfma<float><<<dim3(6,64), blk, 0, stream>>>(yg_bf, WtO, out, BTdim, Cdim, Cdim);
  k9_copy<<<dim3((BTdim*Cdim+255)/256), blk, 0, stream>>>(v1, out + BTC);
}

// Round 7
// 626.283 us; speedup vs baseline: 1.6301x; 1.1018x over previous
//
#include <hip/hip_runtime.h>
#include <hip/hip_bf16.h>
#include <math.h>

#define Bdim 8
#define Tdim 1024
#define Cdim 768
#define Hdim 24
#define Ndim 32
#define BTdim (Bdim*Tdim)
#define CH6 16

typedef __attribute__((ext_vector_type(8))) short bf16x8;
typedef __attribute__((ext_vector_type(4))) float f32x4;
typedef __hip_bfloat16 bf16;

__device__ __forceinline__ float sigm(float x){ return 1.f/(1.f+expf(-x)); }
__device__ __forceinline__ float softplusf(float x){ return fmaxf(x,0.f) + log1pf(expf(-fabsf(x))); }
__device__ __forceinline__ float bf2f(bf16 v){ return __bfloat162float(v); }
__device__ __forceinline__ float us2f(unsigned short s){ return __builtin_bit_cast(float, (unsigned)s<<16); }

template<int CTRL>
__device__ __forceinline__ float dpp_add(float x){
  int xi = __builtin_bit_cast(int, x);
  int yi = __builtin_amdgcn_mov_dpp(xi, CTRL, 0xF, 0xF, true);
  return x + __builtin_bit_cast(float, yi);
}
__device__ __forceinline__ float red32(float x){
  x = dpp_add<0xB1>(x);
  x = dpp_add<0x4E>(x);
  x = dpp_add<0x141>(x);
  x = dpp_add<0x140>(x);
  x += __shfl_xor(x, 16);
  return x;
}
__device__ __forceinline__ void cvt8(uint4 u, float* d){
  d[0]=__builtin_bit_cast(float, u.x<<16); d[1]=__builtin_bit_cast(float, u.x&0xFFFF0000u);
  d[2]=__builtin_bit_cast(float, u.y<<16); d[3]=__builtin_bit_cast(float, u.y&0xFFFF0000u);
  d[4]=__builtin_bit_cast(float, u.z<<16); d[5]=__builtin_bit_cast(float, u.z&0xFFFF0000u);
  d[6]=__builtin_bit_cast(float, u.w<<16); d[7]=__builtin_bit_cast(float, u.w&0xFFFF0000u);
}

#define GLDS16(gp, lp) __builtin_amdgcn_global_load_lds((const __attribute__((address_space(1))) void*)(gp), (__attribute__((address_space(3))) void*)(lp), 16, 0, 0)

// ---------------- K1: token shift ----------------
__global__ void k1_shift(const float* __restrict__ x, const float* __restrict__ maa_x,
                         float* __restrict__ xx, bf16* __restrict__ xxx) {
  int idx = blockIdx.x*256 + threadIdx.x;
  if (idx >= BTdim*Cdim) return;
  int c = idx % Cdim; int row = idx / Cdim; int t = row % Tdim;
  float xv = x[idx];
  float xp = (t==0) ? 0.f : x[idx - Cdim];
  float d = xp - xv;
  xx[idx] = d;
  xxx[idx] = __float2bfloat16(xv + d*maa_x[c]);
}

// ---------------- big weight convert + transpose ----------------
__global__ __launch_bounds__(256) void kconvW(const float* __restrict__ W0, const float* __restrict__ W1,
    const float* __restrict__ W2, const float* __restrict__ W3,
    bf16* __restrict__ T0, bf16* __restrict__ T1, bf16* __restrict__ T2, bf16* __restrict__ T3) {
  const float* Wsrc[4] = {W0,W1,W2,W3};
  bf16* Tdst[4] = {T0,T1,T2,T3};
  const float* W = Wsrc[blockIdx.z];
  bf16* T = Tdst[blockIdx.z];
  __shared__ float tile[32][33];
  int bx = blockIdx.x*32, by = blockIdx.y*32;
  int tx = threadIdx.x & 31, ty = threadIdx.x >> 5;
  #pragma unroll
  for (int q=0;q<32;q+=8) tile[ty+q][tx] = W[(size_t)(by+ty+q)*Cdim + bx+tx];
  __syncthreads();
  #pragma unroll
  for (int q=0;q<32;q+=8) T[(size_t)(bx+ty+q)*Cdim + by+tx] = __float2bfloat16(tile[tx][ty+q]);
}

// ---------------- pack stage-1 and stage-2 small weights (transposed bf16, zero-padded) ----------------
__global__ __launch_bounds__(256) void kprep(const float* __restrict__ dw1, const float* __restrict__ aaa_w1,
    const float* __restrict__ ma_w1, const float* __restrict__ kkk_w1, const float* __restrict__ mk_w1,
    const float* __restrict__ mv_w1, const float* __restrict__ gate_w1, const float* __restrict__ maa_w1,
    const float* __restrict__ dw2, const float* __restrict__ aaa_w2, const float* __restrict__ ma_w2,
    const float* __restrict__ kkk_w2, const float* __restrict__ mk_w2, const float* __restrict__ mv_w2,
    const float* __restrict__ gate_w2,
    bf16* __restrict__ PWwa, bf16* __restrict__ PWk, bf16* __restrict__ PWv,
    bf16* __restrict__ PWrg, bf16* __restrict__ PWmaa,
    bf16* __restrict__ W2wa, bf16* __restrict__ W2k, bf16* __restrict__ W2v, bf16* __restrict__ W2g){
  int idx = blockIdx.x*256 + threadIdx.x;
  if (idx < 491520) {
    int buf = idx / 98304, rem = idx - buf*98304;
    int n = rem / 768, kk = rem - n*768;
    float val = 0.f;
    bf16* dst;
    switch(buf){
      case 0: dst=PWwa; if(n<64) val=dw1[(size_t)kk*64+n]; else if(n<88) val=aaa_w1[(size_t)kk*24+(n-64)]; else if(n<112) val=ma_w1[(size_t)kk*24+(n-88)]; break;
      case 1: dst=PWk;  if(n<24) val=kkk_w1[(size_t)kk*24+n]; else if(n<48) val=mk_w1[(size_t)kk*24+(n-24)]; break;
      case 2: dst=PWv;  if(n<24) val=mv_w1[(size_t)kk*24+n]; break;
      case 3: dst=PWrg; if(n<120) val=gate_w1[(size_t)kk*120+n]; break;
      default: dst=PWmaa; if(n<112) val=maa_w1[(size_t)kk*112+n]; break;
    }
    dst[rem] = __float2bfloat16(val);
    return;
  }
  int i = idx - 491520;
  if (i < 294912){            // W2wa [2304][128]
    int n=i>>7, q=i&127, seg=n/768, c=n-seg*768;
    float val=0.f;
    if (seg==0){ if(q<64) val=dw2[(size_t)q*768+c]; }
    else if (seg==1){ if(q>=64&&q<88) val=aaa_w2[(size_t)(q-64)*768+c]; }
    else { if(q>=88&&q<112) val=ma_w2[(size_t)(q-88)*768+c]; }
    W2wa[i]=__float2bfloat16(val); return;
  }
  i -= 294912;
  if (i < 98304){             // W2k [1536][64]
    int n=i>>6, q=i&63, seg=n/768, c=n-seg*768;
    float val=0.f;
    if (seg==0){ if(q<24) val=kkk_w2[(size_t)q*768+c]; }
    else { if(q>=24&&q<48) val=mk_w2[(size_t)(q-24)*768+c]; }
    W2k[i]=__float2bfloat16(val); return;
  }
  i -= 98304;
  if (i < 24576){             // W2v [768][32]
    int c=i>>5, q=i&31;
    float val = (q<24) ? mv_w2[(size_t)q*768+c] : 0.f;
    W2v[i]=__float2bfloat16(val); return;
  }
  i -= 24576;
  if (i < 98304){             // W2g [768][128]
    int c=i>>7, q=i&127;
    float val = (q<120) ? gate_w2[(size_t)q*768+c] : 0.f;
    W2g[i]=__float2bfloat16(val);
  }
}

// ---------------- big bf16 MFMA GEMM, templated output dtype ----------------
template<typename OutT>
__global__ __launch_bounds__(256) void gemm_mfma(const bf16* __restrict__ A,
    const bf16* __restrict__ Bt, OutT* __restrict__ C, int M, int N, int K) {
  __shared__ unsigned short As[128*32];
  __shared__ unsigned short Bs[128*32];
  const int bm = blockIdx.y*128, bn = blockIdx.x*128;
  const int tid = threadIdx.x, lane = tid&63, w = tid>>6;
  const int wr = w>>1, wc = w&1;
  const int lr = lane&15, kg = lane>>4;
  f32x4 zero = {0.f,0.f,0.f,0.f};
  f32x4 acc[4][4];
  #pragma unroll
  for (int m=0;m<4;m++)
    #pragma unroll
    for (int n=0;n<4;n++) acc[m][n]=zero;
  const size_t rowA = (size_t)(bm + w*32 + (lane>>2))*K + (lane&3)*8;
  const size_t rowB = (size_t)(bn + w*32 + (lane>>2))*K + (lane&3)*8;
  unsigned short* lA = As + w*32*32;
  unsigned short* lB = Bs + w*32*32;
  for (int k0=0; k0<K; k0+=32){
    GLDS16(A + rowA + k0,                 lA);
    GLDS16(A + rowA + k0 + (size_t)16*K,  lA + 512);
    GLDS16(Bt + rowB + k0,                lB);
    GLDS16(Bt + rowB + k0 + (size_t)16*K, lB + 512);
    __syncthreads();
    bf16x8 af[4], bfr[4];
    #pragma unroll
    for (int m=0;m<4;m++) af[m]  = *(const bf16x8*)(void*)(As + (wr*64+m*16+lr)*32 + kg*8);
    #pragma unroll
    for (int n=0;n<4;n++) bfr[n] = *(const bf16x8*)(void*)(Bs + (wc*64+n*16+lr)*32 + kg*8);
    #pragma unroll
    for (int m=0;m<4;m++)
      #pragma unroll
      for (int n=0;n<4;n++)
        acc[m][n] = __builtin_amdgcn_mfma_f32_16x16x32_bf16(af[m], bfr[n], acc[m][n], 0,0,0);
    __syncthreads();
  }
  #pragma unroll
  for (int m=0;m<4;m++)
    #pragma unroll
    for (int n=0;n<4;n++){
      size_t r0 = (size_t)(bm + wr*64 + m*16 + kg*4);
      int cc = bn + wc*64 + n*16 + lr;
      #pragma unroll
      for (int q=0;q<4;q++){
        float val = acc[m][n][q];
        if constexpr (sizeof(OutT)==2) C[(r0+q)*N + cc] = __float2bfloat16(val);
        else                           C[(r0+q)*N + cc] = val;
      }
    }
}

// ---------------- gemm_tm: f32 out, N=112, tanh ----------------
__global__ __launch_bounds__(256) void gemm_tm(const bf16* __restrict__ A,
    const bf16* __restrict__ Bt, float* __restrict__ C, int K) {
  __shared__ unsigned short As[128*32];
  __shared__ unsigned short Bs[128*32];
  const int bm = blockIdx.y*128;
  const int tid = threadIdx.x, lane = tid&63, w = tid>>6;
  const int wr = w>>1, wc = w&1;
  const int lr = lane&15, kg = lane>>4;
  f32x4 zero = {0.f,0.f,0.f,0.f};
  f32x4 acc[4][4];
  #pragma unroll
  for (int m=0;m<4;m++)
    #pragma unroll
    for (int n=0;n<4;n++) acc[m][n]=zero;
  const size_t rowA = (size_t)(bm + w*32 + (lane>>2))*K + (lane&3)*8;
  const size_t rowB = (size_t)(w*32 + (lane>>2))*K + (lane&3)*8;
  unsigned short* lA = As + w*32*32;
  unsigned short* lB = Bs + w*32*32;
  for (int k0=0; k0<K; k0+=32){
    GLDS16(A + rowA + k0,                 lA);
    GLDS16(A + rowA + k0 + (size_t)16*K,  lA + 512);
    GLDS16(Bt + rowB + k0,                lB);
    GLDS16(Bt + rowB + k0 + (size_t)16*K, lB + 512);
    __syncthreads();
    bf16x8 af[4], bfr[4];
    #pragma unroll
    for (int m=0;m<4;m++) af[m]  = *(const bf16x8*)(void*)(As + (wr*64+m*16+lr)*32 + kg*8);
    #pragma unroll
    for (int n=0;n<4;n++) bfr[n] = *(const bf16x8*)(void*)(Bs + (wc*64+n*16+lr)*32 + kg*8);
    #pragma unroll
    for (int m=0;m<4;m++)
      #pragma unroll
      for (int n=0;n<4;n++)
        acc[m][n] = __builtin_amdgcn_mfma_f32_16x16x32_bf16(af[m], bfr[n], acc[m][n], 0,0,0);
    __syncthreads();
  }
  #pragma unroll
  for (int m=0;m<4;m++)
    #pragma unroll
    for (int n=0;n<4;n++){
      size_t r0 = (size_t)(bm + wr*64 + m*16 + kg*4);
      int cc = wc*64 + n*16 + lr;
      if (cc < 112){
        #pragma unroll
        for (int q=0;q<4;q++)
          C[(r0+q)*112 + cc] = tanhf(acc[m][n][q]);
      }
    }
}

// ---------------- stage-1 batched small GEMM -> bf16 padded, per-z activation ----------------
struct S1P {
  const bf16* A[4];
  const bf16* Bt[4];
  bf16* C[4];
  int Ntrue[4];
  int Nalloc[4];
  int act[4];
};
__global__ __launch_bounds__(256) void gemm_s1(S1P p, int K) {
  const int z = blockIdx.z;
  const bf16* __restrict__ A  = p.A[z];
  const bf16* __restrict__ Bt = p.Bt[z];
  bf16* __restrict__ C = p.C[z];
  const int Ntrue = p.Ntrue[z], Nalloc = p.Nalloc[z], act = p.act[z];
  __shared__ unsigned short As[128*32];
  __shared__ unsigned short Bs[128*32];
  const int bm = blockIdx.y*128;
  const int tid = threadIdx.x, lane = tid&63, w = tid>>6;
  const int wr = w>>1, wc = w&1;
  const int lr = lane&15, kg = lane>>4;
  f32x4 zero = {0.f,0.f,0.f,0.f};
  f32x4 acc[4][4];
  #pragma unroll
  for (int m=0;m<4;m++)
    #pragma unroll
    for (int n=0;n<4;n++) acc[m][n]=zero;
  const size_t rowA = (size_t)(bm + w*32 + (lane>>2))*K + (lane&3)*8;
  const size_t rowB = (size_t)(w*32 + (lane>>2))*K + (lane&3)*8;
  unsigned short* lA = As + w*32*32;
  unsigned short* lB = Bs + w*32*32;
  for (int k0=0; k0<K; k0+=32){
    GLDS16(A + rowA + k0,                 lA);
    GLDS16(A + rowA + k0 + (size_t)16*K,  lA + 512);
    GLDS16(Bt + rowB + k0,                lB);
    GLDS16(Bt + rowB + k0 + (size_t)16*K, lB + 512);
    __syncthreads();
    bf16x8 af[4], bfr[4];
    #pragma unroll
    for (int m=0;m<4;m++) af[m]  = *(const bf16x8*)(void*)(As + (wr*64+m*16+lr)*32 + kg*8);
    #pragma unroll
    for (int n=0;n<4;n++) bfr[n] = *(const bf16x8*)(void*)(Bs + (wc*64+n*16+lr)*32 + kg*8);
    #pragma unroll
    for (int m=0;m<4;m++)
      #pragma unroll
      for (int n=0;n<4;n++)
        acc[m][n] = __builtin_amdgcn_mfma_f32_16x16x32_bf16(af[m], bfr[n], acc[m][n], 0,0,0);
    __syncthreads();
  }
  #pragma unroll
  for (int m=0;m<4;m++)
    #pragma unroll
    for (int n=0;n<4;n++){
      size_t r0 = (size_t)(bm + wr*64 + m*16 + kg*4);
      int cc = wc*64 + n*16 + lr;
      if (cc < Nalloc){
        #pragma unroll
        for (int q=0;q<4;q++){
          float val = acc[m][n][q];
          if      (act==1){ if (cc<64) val = tanhf(val); }
          else if (act==2){ if (cc<24) val = tanhf(val); }
          else if (act==3){ val = sigm(val); }
          if (cc >= Ntrue) val = 0.f;
          C[(r0+q)*Nalloc + cc] = __float2bfloat16(val);
        }
      }
    }
}

// ---------------- stage-2 batched GEMM: z = h @ W2 -> bf16 ----------------
struct Z4 {
  const bf16* A[4];
  const bf16* Bt[4];
  bf16* C[4];
  int N[4];
  int K[4];
};
__global__ __launch_bounds__(256) void gemm_z(Z4 p) {
  const int z = blockIdx.z;
  const int N = p.N[z], K = p.K[z];
  const int bn = blockIdx.x*128;
  if (bn >= N) return;
  const bf16* __restrict__ A  = p.A[z];
  const bf16* __restrict__ Bt = p.Bt[z];
  bf16* __restrict__ C = p.C[z];
  __shared__ unsigned short As[128*32];
  __shared__ unsigned short Bs[128*32];
  const int bm = blockIdx.y*128;
  const int tid = threadIdx.x, lane = tid&63, w = tid>>6;
  const int wr = w>>1, wc = w&1;
  const int lr = lane&15, kg = lane>>4;
  f32x4 zero = {0.f,0.f,0.f,0.f};
  f32x4 acc[4][4];
  #pragma unroll
  for (int m=0;m<4;m++)
    #pragma unroll
    for (int n=0;n<4;n++) acc[m][n]=zero;
  const size_t rowA = (size_t)(bm + w*32 + (lane>>2))*K + (lane&3)*8;
  const size_t rowB = (size_t)(bn + w*32 + (lane>>2))*K + (lane&3)*8;
  unsigned short* lA = As + w*32*32;
  unsigned short* lB = Bs + w*32*32;
  for (int k0=0; k0<K; k0+=32){
    GLDS16(A + rowA + k0,                 lA);
    GLDS16(A + rowA + k0 + (size_t)16*K,  lA + 512);
    GLDS16(Bt + rowB + k0,                lB);
    GLDS16(Bt + rowB + k0 + (size_t)16*K, lB + 512);
    __syncthreads();
    bf16x8 af[4], bfr[4];
    #pragma unroll
    for (int m=0;m<4;m++) af[m]  = *(const bf16x8*)(void*)(As + (wr*64+m*16+lr)*32 + kg*8);
    #pragma unroll
    for (int n=0;n<4;n++) bfr[n] = *(const bf16x8*)(void*)(Bs + (wc*64+n*16+lr)*32 + kg*8);
    #pragma unroll
    for (int m=0;m<4;m++)
      #pragma unroll
      for (int n=0;n<4;n++)
        acc[m][n] = __builtin_amdgcn_mfma_f32_16x16x32_bf16(af[m], bfr[n], acc[m][n], 0,0,0);
    __syncthreads();
  }
  #pragma unroll
  for (int m=0;m<4;m++)
    #pragma unroll
    for (int n=0;n<4;n++){
      size_t r0 = (size_t)(bm + wr*64 + m*16 + kg*4);
      int cc = bn + wc*64 + n*16 + lr;
      #pragma unroll
      for (int q=0;q<4;q++)
        C[(r0+q)*N + cc] = __float2bfloat16(acc[m][n][q]);
    }
}

// ---------------- K2b: mix, 8 rows per block (round-4 form; tm pre-tanh'd) ----------------
__global__ __launch_bounds__(256) void k2_mix(const float* __restrict__ x, const float* __restrict__ xx,
    const float* __restrict__ tm, const float* __restrict__ w2,
    const float* __restrict__ mrg, const float* __restrict__ mwa,
    const float* __restrict__ mk_, const float* __restrict__ mv_,
    bf16* __restrict__ xrg, bf16* __restrict__ xwa, bf16* __restrict__ xk, bf16* __restrict__ xv) {
  const int row0 = blockIdx.x*8, tid = threadIdx.x;
  __shared__ float stm[8][112];
  for (int idx=tid; idx<8*112; idx+=256){
    int rr=idx/112, q=idx-rr*112;
    stm[rr][q]=tm[(size_t)(row0+rr)*112+q];
  }
  __syncthreads();
  for (int c=tid;c<Cdim;c+=256){
    float x8[8], d8[8];
    #pragma unroll
    for (int rr=0;rr<8;rr++){
      size_t i=(size_t)(row0+rr)*Cdim+c;
      x8[rr]=x[i]; d8[rr]=xx[i];
    }
    float mrgc=mrg[c], mwac=mwa[c], mkc=mk_[c], mvc=mv_[c];
    float m0[8]={},m1[8]={},m2[8]={},m3[8]={};
    #pragma unroll 4
    for (int d=0; d<28; d++){
      float w0=w2[(size_t)(d)*Cdim + c];
      float w1=w2[(size_t)(28+d)*Cdim + c];
      float w2v=w2[(size_t)(56+d)*Cdim + c];
      float w3=w2[(size_t)(84+d)*Cdim + c];
      #pragma unroll
      for (int rr=0;rr<8;rr++){
        m0[rr]+=stm[rr][d]*w0; m1[rr]+=stm[rr][28+d]*w1;
        m2[rr]+=stm[rr][56+d]*w2v; m3[rr]+=stm[rr][84+d]*w3;
      }
    }
    #pragma unroll
    for (int rr=0;rr<8;rr++){
      size_t i=(size_t)(row0+rr)*Cdim+c;
      xrg[i]=__float2bfloat16(x8[rr] + d8[rr]*(mrgc+m0[rr]));
      xwa[i]=__float2bfloat16(x8[rr] + d8[rr]*(mwac+m1[rr]));
      xk[i] =__float2bfloat16(x8[rr] + d8[rr]*(mkc+m2[rr]));
      xv[i] =__float2bfloat16(x8[rr] + d8[rr]*(mvc+m3[rr]));
    }
  }
}

// ---------------- K5 v3: pure elementwise + in-wave head norm ----------------
__global__ __launch_bounds__(256) void k5_fuse(
    const bf16* __restrict__ zwa, const bf16* __restrict__ zk, const bf16* __restrict__ zv,
    const float* __restrict__ td, const float* __restrict__ aaaaa,
    const float* __restrict__ misc_a, const float* __restrict__ misc_k, const float* __restrict__ misc_v,
    const float* __restrict__ v1,
    float* __restrict__ kbuf, float* __restrict__ vbuf, float* __restrict__ wexp,
    bf16* __restrict__ kb_bf, bf16* __restrict__ vb_bf,
    bf16* __restrict__ akv, bf16* __restrict__ bkv) {
  const int row = blockIdx.x, tid = threadIdx.x;
  float kraw[3], v0[3], v1v[3];
  #pragma unroll
  for (int it=0;it<3;it++){
    size_t i=(size_t)row*Cdim + tid + it*256;
    kraw[it]=kbuf[i]; v0[it]=vbuf[i]; v1v[it]=v1[i];
  }
  __syncthreads();   // all f32 reads of kbuf/vbuf done before bf16 overlay writes
  #pragma unroll
  for (int it=0;it<3;it++){
    const int c = tid + it*256;
    const size_t i=(size_t)row*Cdim+c;
    float zd = bf2f(zwa[(size_t)row*2304 + c]);
    float za = bf2f(zwa[(size_t)row*2304 + 768 + c]);
    float zma= bf2f(zwa[(size_t)row*2304 + 1536 + c]);
    float zkk= bf2f(zk[(size_t)row*1536 + c]);
    float zmk= bf2f(zk[(size_t)row*1536 + 768 + c]);
    float zmv= bf2f(zv[i]);
    float w = -softplusf(-(td[c]+zd)) - 0.5f;
    wexp[i] = expf(-expf(w));
    float a  = sigm(aaaaa[c]+za);
    float ma = sigm(misc_a[c]+zma);
    float mk = sigm(misc_k[c]+zmk);
    float mv = sigm(misc_v[c]+zmv);
    vb_bf[i] = __float2bfloat16(v0[it] + (v1v[it]-v0[it])*mv);
    float kf = kraw[it]*(ma + a*(1.f-ma))*expf(fminf(w*mk,0.f));
    kb_bf[i] = __float2bfloat16(kf);
    float kk = kraw[it] + zkk;
    float ss = red32(kk*kk);
    float kkn = kk * (1.f/fmaxf(sqrtf(ss),1e-12f));
    akv[i] = __float2bfloat16(-kkn);
    bkv[i] = __float2bfloat16(kkn*a);
  }
}

// ---------------- K6 v6: 1 head / 128-thread block (2 waves on 2 SIMDs) ----------------
// lane (tid) -> row i0 = tid>>2 (0..31), col group jq = tid&3 (8 cols).
// Wave-PRIVATE GLDS staging (no __syncthreads ever; vmcnt is wave-synchronous).
// Register software pipeline: LOADT(t+1) issued before compute of t.
__global__ __launch_bounds__(128) void k6_wkv(const unsigned short* __restrict__ r, const float* __restrict__ wd,
    const unsigned short* __restrict__ k, const unsigned short* __restrict__ v,
    const unsigned short* __restrict__ a, const unsigned short* __restrict__ b2, float* __restrict__ y) {
  const int tid = threadIdx.x;
  const int wvi = tid >> 6;          // wave id (uniform per wave)
  const int lane = tid & 63;
  const int head = blockIdx.x;
  const int bb = head / Hdim, hh = head - bb*Hdim;
  const int i0 = tid >> 2;           // row 0..31
  const int jq = tid & 3;
  const int col = jq*8;
  __shared__ __align__(16) float swd[2][2][CH6][Ndim];                 // [wave][buf] 8 KB
  __shared__ __align__(16) unsigned short sbf[2][2][4][CH6][Ndim];     // r,k,a,b   16 KB
  __shared__ __align__(16) unsigned short sv2[2][2][CH6][Ndim];        // v          4 KB
  const unsigned short* gb16[4] = {r, k, a, b2};
  const size_t gbase = (size_t)bb*Tdim*Cdim + (size_t)hh*Ndim;
  float S[8];
  #pragma unroll
  for (int m=0;m<8;m++) S[m]=0.f;

  auto STAGE = [&](int c, int buf){
    const size_t tb = (size_t)c*CH6;
    GLDS16(wd + gbase + (tb +   (lane>>3))*Cdim + (lane&7)*4, &swd[wvi][buf][0][0]);
    GLDS16(wd + gbase + (tb + 8+(lane>>3))*Cdim + (lane&7)*4, &swd[wvi][buf][8][0]);
    #pragma unroll
    for (int arr=0; arr<4; arr++)
      GLDS16(gb16[arr] + gbase + (tb + (lane>>2))*Cdim + (lane&3)*8, &sbf[wvi][buf][arr][0][0]);
    GLDS16(v + gbase + (tb + (lane>>2))*Cdim + (lane&3)*8, &sv2[wvi][buf][0][0]);
  };

  uint4 nr, nk, na, nb; float4 nw0, nw1; unsigned short nv;
  auto LOADT = [&](int buf, int t){
    nr  = *(const uint4*)&sbf[wvi][buf][0][t][col];
    nk  = *(const uint4*)&sbf[wvi][buf][1][t][col];
    na  = *(const uint4*)&sbf[wvi][buf][2][t][col];
    nb  = *(const uint4*)&sbf[wvi][buf][3][t][col];
    nw0 = *(const float4*)&swd[wvi][buf][t][col];
    nw1 = *(const float4*)&swd[wvi][buf][t][col+4];
    nv  = sv2[wvi][buf][t][i0];
  };

  STAGE(0, 0);
  asm volatile("s_waitcnt vmcnt(0)" ::: "memory");
  LOADT(0, 0);
  int buf = 0;
  const int NCH = Tdim/CH6;
  for (int c=0; c<NCH; ++c){
    if (c+1 < NCH) STAGE(c+1, buf^1);
    const size_t yb = gbase + (size_t)c*CH6*Cdim;
    #pragma unroll
    for (int t=0; t<CH6; t++){
      uint4 cr=nr, ck=nk, ca=na, cb=nb;
      float4 cw0=nw0, cw1=nw1;
      unsigned short cv=nv;
      if (t < CH6-1) LOADT(buf, t+1);       // prefetch next step (raw)
      float av[8]; cvt8(ca, av);
      float sa=0.f;
      #pragma unroll
      for (int j=0;j<8;j++) sa += S[j]*av[j];
      sa = dpp_add<0xB1>(sa); sa = dpp_add<0x4E>(sa);
      float wvv[8] = {cw0.x,cw0.y,cw0.z,cw0.w,cw1.x,cw1.y,cw1.z,cw1.w};
      float kv[8]; cvt8(ck, kv);
      float bv[8]; cvt8(cb, bv);
      float rv[8]; cvt8(cr, rv);
      const float vl = us2f(cv);
      float yv=0.f;
      #pragma unroll
      for (int j=0;j<8;j++){
        S[j] = S[j]*wvv[j] + (sa*bv[j] + vl*kv[j]);
        yv += S[j]*rv[j];
      }
      yv = dpp_add<0xB1>(yv); yv = dpp_add<0x4E>(yv);
      if (jq == 0) y[yb + (size_t)t*Cdim + i0] = yv;
      if (t == CH6-1 && c+1 < NCH){
        asm volatile("s_waitcnt vmcnt(0)" ::: "memory");
        LOADT(buf^1, 0);                    // first step of next chunk
      }
    }
    buf ^= 1;
  }
}

// ---------------- K7 v3: GroupNorm + bonus + gate (bf16 inputs) ----------------
__global__ __launch_bounds__(256) void k7_post(const float* __restrict__ y,
    const bf16* __restrict__ r, const bf16* __restrict__ kf, const bf16* __restrict__ v,
    const bf16* __restrict__ g, const float* __restrict__ faaaa,
    const float* __restrict__ lnw, const float* __restrict__ lnb,
    bf16* __restrict__ ygate) {
  const int row = blockIdx.x, tid = threadIdx.x;
  #pragma unroll
  for (int it=0; it<3; it++){
    const int c = tid + it*256;
    const size_t i = (size_t)row*Cdim + c;
    float yv = y[i];
    float bon = bf2f(r[i])*bf2f(kf[i])*faaaa[c];
    float s  = red32(yv);
    float ss = red32(yv*yv);
    float bn = red32(bon);
    float mu = s*(1.f/Ndim);
    float var = ss*(1.f/Ndim) - mu*mu;
    float rs = rsqrtf(var + 6.4e-5f);
    float yn = (yv-mu)*rs*lnw[c]+lnb[c];
    ygate[i]=__float2bfloat16((yn + bn*bf2f(v[i]))*bf2f(g[i]));
  }
}

// ---------------- K9: v1 passthrough ----------------
__global__ void k9_copy(const float* __restrict__ src, float* __restrict__ dst){
  int idx = blockIdx.x*256 + threadIdx.x;
  if (idx < BTdim*Cdim) dst[idx]=src[idx];
}

extern "C" void kernel_launch(void* const* d_in, const int* in_sizes, int n_in,
                              void* d_out, int out_size, void* d_ws, size_t ws_size,
                              hipStream_t stream) {
  const float* x      = (const float*)d_in[0];
  const float* v1     = (const float*)d_in[1];
  const float* maa_x  = (const float*)d_in[2];
  const float* maa_rg = (const float*)d_in[3];
  const float* maa_wa = (const float*)d_in[4];
  const float* maa_k  = (const float*)d_in[5];
  const float* maa_v  = (const float*)d_in[6];
  const float* time_decay = (const float*)d_in[7];
  const float* faaaa  = (const float*)d_in[8];
  const float* aaaaa  = (const float*)d_in[9];
  const float* maa_w1 = (const float*)d_in[10];
  const float* maa_w2 = (const float*)d_in[11];
  const float* dw1    = (const float*)d_in[12];
  const float* dw2    = (const float*)d_in[13];
  const float* aaa_w1 = (const float*)d_in[14];
  const float* aaa_w2 = (const float*)d_in[15];
  const float* kkk_w1 = (const float*)d_in[16];
  const float* kkk_w2 = (const float*)d_in[17];
  const float* gate_w1= (const float*)d_in[18];
  const float* gate_w2= (const float*)d_in[19];
  const float* ma_w1  = (const float*)d_in[20];
  const float* ma_w2  = (const float*)d_in[21];
  const float* misc_a = (const float*)d_in[22];
  const float* mk_w1  = (const float*)d_in[23];
  const float* mk_w2  = (const float*)d_in[24];
  const float* misc_k = (const float*)d_in[25];
  const float* mv_w1  = (const float*)d_in[26];
  const float* mv_w2  = (const float*)d_in[27];
  const float* misc_v = (const float*)d_in[28];
  const float* Wr     = (const float*)d_in[29];
  const float* Wk     = (const float*)d_in[30];
  const float* Wv     = (const float*)d_in[31];
  const float* Wo     = (const float*)d_in[32];
  const float* lnw    = (const float*)d_in[33];
  const float* lnb    = (const float*)d_in[34];
  float* out = (float*)d_out;

  float* ws = (float*)d_ws;
  const size_t BTC = (size_t)BTdim*Cdim;   // 6291456
  const size_t HB  = BTC/2;                // 3145728
  float* xx   = ws;                float* wexp = ws;
  float* kb   = ws + 2*HB;         bf16* kb_bf = (bf16*)kb;
  float* vb   = ws + 4*HB;         bf16* vb_bf = (bf16*)vb;
  bf16* xrg_bf = (bf16*)(ws + 6*HB);
  bf16* xwa_bf = xrg_bf + BTC;
  bf16* zwa_bf = (bf16*)(ws + 6*HB);
  bf16* xk_bf  = (bf16*)(ws + 9*HB);
  bf16* xv_bf  = xk_bf + BTC;
  bf16* zk_bf  = (bf16*)(ws + 9*HB);
  bf16* xxx_bf = (bf16*)(ws + 11*HB);
  bf16* zv_bf  = (bf16*)(ws + 11*HB);
  float* tm    = ws + 12*HB;
  bf16* zg_bf  = (bf16*)(ws + 12*HB);
  bf16* hwa_bf = (bf16*)(ws + 13*HB);
  bf16* hk_bf  = hwa_bf + (size_t)BTdim*128;
  bf16* hv_bf  = hk_bf  + (size_t)BTdim*64;
  bf16* hrg_bf = hv_bf  + (size_t)BTdim*32;
  bf16* akv_bf = (bf16*)(ws + 13*HB);
  bf16* bkv_bf = (bf16*)(ws + 14*HB);
  bf16* yg_bf  = (bf16*)(ws + 14*HB);
  float* ybuf  = ws + 15*HB;
  bf16* rb_bf  = (bf16*)(ws + 17*HB);
  bf16* Wbase  = (bf16*)(ws + 18*HB);
  bf16* WtR = Wbase;
  bf16* WtK = WtR + 589824;
  bf16* WtV = WtK + 589824;
  bf16* WtO = WtV + 589824;
  bf16* PWwa = WtO + 589824;
  bf16* PWk  = PWwa + 98304;
  bf16* PWv  = PWk  + 98304;
  bf16* PWrg = PWv  + 98304;
  bf16* PWmaa= PWrg + 98304;
  bf16* W2wa = PWmaa + 98304;
  bf16* W2k  = W2wa + 294912;
  bf16* W2v  = W2k  + 98304;
  bf16* W2g  = W2v  + 24576;

  dim3 blk(256);
  kconvW<<<dim3(24,24,4), blk, 0, stream>>>(Wr,Wk,Wv,Wo, WtR,WtK,WtV,WtO);
  kprep<<<dim3(3936), blk, 0, stream>>>(dw1,aaa_w1,ma_w1,kkk_w1,mk_w1,mv_w1,gate_w1,maa_w1,
                                        dw2,aaa_w2,ma_w2,kkk_w2,mk_w2,mv_w2,gate_w2,
                                        PWwa,PWk,PWv,PWrg,PWmaa, W2wa,W2k,W2v,W2g);
  k1_shift<<<dim3((BTdim*Cdim+255)/256), blk, 0, stream>>>(x, maa_x, xx, xxx_bf);
  gemm_tm<<<dim3(1,64), blk, 0, stream>>>(xxx_bf, PWmaa, tm, Cdim);
  k2_mix<<<dim3(BTdim/8), blk, 0, stream>>>(x, xx, tm, maa_w2, maa_rg, maa_wa, maa_k, maa_v,
                                            xrg_bf, xwa_bf, xk_bf, xv_bf);
  {
    S1P p{};
    p.A[0]=xwa_bf; p.Bt[0]=PWwa; p.C[0]=hwa_bf; p.Ntrue[0]=112; p.Nalloc[0]=128; p.act[0]=1;
    p.A[1]=xk_bf;  p.Bt[1]=PWk;  p.C[1]=hk_bf;  p.Ntrue[1]=48;  p.Nalloc[1]=64;  p.act[1]=2;
    p.A[2]=xv_bf;  p.Bt[2]=PWv;  p.C[2]=hv_bf;  p.Ntrue[2]=24;  p.Nalloc[2]=32;  p.act[2]=0;
    p.A[3]=xrg_bf; p.Bt[3]=PWrg; p.C[3]=hrg_bf; p.Ntrue[3]=120; p.Nalloc[3]=128; p.act[3]=3;
    gemm_s1<<<dim3(1,64,4), blk, 0, stream>>>(p, Cdim);
  }
  gemm_mfma<bf16> <<<dim3(6,64), blk, 0, stream>>>(xrg_bf, WtR, rb_bf, BTdim, Cdim, Cdim);
  gemm_mfma<float><<<dim3(6,64), blk, 0, stream>>>(xk_bf,  WtK, kb,    BTdim, Cdim, Cdim);
  gemm_mfma<float><<<dim3(6,64), blk, 0, stream>>>(xv_bf,  WtV, vb,    BTdim, Cdim, Cdim);
  {
    Z4 p{};
    p.A[0]=hwa_bf; p.Bt[0]=W2wa; p.C[0]=zwa_bf; p.N[0]=2304; p.K[0]=128;
    p.A[1]=hk_bf;  p.Bt[1]=W2k;  p.C[1]=zk_bf;  p.N[1]=1536; p.K[1]=64;
    p.A[2]=hv_bf;  p.Bt[2]=W2v;  p.C[2]=zv_bf;  p.N[2]=768;  p.K[2]=32;
    p.A[3]=hrg_bf; p.Bt[3]=W2g;  p.C[3]=zg_bf;  p.N[3]=768;  p.K[3]=128;
    gemm_z<<<dim3(18,64,4), blk, 0, stream>>>(p);
  }
  k5_fuse<<<dim3(BTdim), blk, 0, stream>>>(zwa_bf, zk_bf, zv_bf,
      time_decay, aaaaa, misc_a, misc_k, misc_v, v1,
      kb, vb, wexp, kb_bf, vb_bf, akv_bf, bkv_bf);
  k6_wkv<<<dim3(Bdim*Hdim), dim3(128), 0, stream>>>((const unsigned short*)rb_bf, wexp,
      (const unsigned short*)kb_bf, (const unsigned short*)vb_bf,
      (const unsigned short*)akv_bf, (const unsigned short*)bkv_bf, ybuf);
  k7_post<<<dim3(BTdim), blk, 0, stream>>>(ybuf, rb_bf, kb_bf, vb_bf, zg_bf, faaaa, lnw, lnb, yg_bf);
  gemm_mfma<float><<<dim3(6,64), blk, 0, stream>>>(yg_bf, WtO, out, BTdim, Cdim, Cdim);
  k9_copy<<<dim3((BTdim*Cdim+255)/256), blk, 0, stream>>>(v1, out + BTC);
}

// Round 8
// 538.184 us; speedup vs baseline: 1.8969x; 1.1637x over previous
//
#include <hip/hip_runtime.h>
#include <hip/hip_bf16.h>
#include <math.h>

#define Bdim 8
#define Tdim 1024
#define Cdim 768
#define Hdim 24
#define Ndim 32
#define BTdim (Bdim*Tdim)
#define CH6 16

typedef __attribute__((ext_vector_type(8))) short bf16x8;
typedef __attribute__((ext_vector_type(4))) float f32x4;
typedef __hip_bfloat16 bf16;

__device__ __forceinline__ float sigm(float x){ return 1.f/(1.f+expf(-x)); }
__device__ __forceinline__ float softplusf(float x){ return fmaxf(x,0.f) + log1pf(expf(-fabsf(x))); }
__device__ __forceinline__ float bf2f(bf16 v){ return __bfloat162float(v); }
__device__ __forceinline__ float us2f(unsigned short s){ return __builtin_bit_cast(float, (unsigned)s<<16); }

template<int CTRL>
__device__ __forceinline__ float dpp_add(float x){
  int xi = __builtin_bit_cast(int, x);
  int yi = __builtin_amdgcn_mov_dpp(xi, CTRL, 0xF, 0xF, true);
  return x + __builtin_bit_cast(float, yi);
}
__device__ __forceinline__ float red32(float x){
  x = dpp_add<0xB1>(x);
  x = dpp_add<0x4E>(x);
  x = dpp_add<0x141>(x);
  x = dpp_add<0x140>(x);
  x += __shfl_xor(x, 16);
  return x;
}
// sum over each 16-lane row (all lanes receive the result)
__device__ __forceinline__ float red16(float x){
  x = dpp_add<0xB1>(x);
  x = dpp_add<0x4E>(x);
  x = dpp_add<0x141>(x);
  x = dpp_add<0x140>(x);
  return x;
}
__device__ __forceinline__ void cvt8(uint4 u, float* d){
  d[0]=__builtin_bit_cast(float, u.x<<16); d[1]=__builtin_bit_cast(float, u.x&0xFFFF0000u);
  d[2]=__builtin_bit_cast(float, u.y<<16); d[3]=__builtin_bit_cast(float, u.y&0xFFFF0000u);
  d[4]=__builtin_bit_cast(float, u.z<<16); d[5]=__builtin_bit_cast(float, u.z&0xFFFF0000u);
  d[6]=__builtin_bit_cast(float, u.w<<16); d[7]=__builtin_bit_cast(float, u.w&0xFFFF0000u);
}

#define GLDS16(gp, lp) __builtin_amdgcn_global_load_lds((const __attribute__((address_space(1))) void*)(gp), (__attribute__((address_space(3))) void*)(lp), 16, 0, 0)

// ---------------- K1: token shift ----------------
__global__ void k1_shift(const float* __restrict__ x, const float* __restrict__ maa_x,
                         float* __restrict__ xx, bf16* __restrict__ xxx) {
  int idx = blockIdx.x*256 + threadIdx.x;
  if (idx >= BTdim*Cdim) return;
  int c = idx % Cdim; int row = idx / Cdim; int t = row % Tdim;
  float xv = x[idx];
  float xp = (t==0) ? 0.f : x[idx - Cdim];
  float d = xp - xv;
  xx[idx] = d;
  xxx[idx] = __float2bfloat16(xv + d*maa_x[c]);
}

// ---------------- big weight convert + transpose ----------------
__global__ __launch_bounds__(256) void kconvW(const float* __restrict__ W0, const float* __restrict__ W1,
    const float* __restrict__ W2, const float* __restrict__ W3,
    bf16* __restrict__ T0, bf16* __restrict__ T1, bf16* __restrict__ T2, bf16* __restrict__ T3) {
  const float* Wsrc[4] = {W0,W1,W2,W3};
  bf16* Tdst[4] = {T0,T1,T2,T3};
  const float* W = Wsrc[blockIdx.z];
  bf16* T = Tdst[blockIdx.z];
  __shared__ float tile[32][33];
  int bx = blockIdx.x*32, by = blockIdx.y*32;
  int tx = threadIdx.x & 31, ty = threadIdx.x >> 5;
  #pragma unroll
  for (int q=0;q<32;q+=8) tile[ty+q][tx] = W[(size_t)(by+ty+q)*Cdim + bx+tx];
  __syncthreads();
  #pragma unroll
  for (int q=0;q<32;q+=8) T[(size_t)(bx+ty+q)*Cdim + by+tx] = __float2bfloat16(tile[tx][ty+q]);
}

// ---------------- pack stage-1 and stage-2 small weights (transposed bf16, zero-padded) ----------------
__global__ __launch_bounds__(256) void kprep(const float* __restrict__ dw1, const float* __restrict__ aaa_w1,
    const float* __restrict__ ma_w1, const float* __restrict__ kkk_w1, const float* __restrict__ mk_w1,
    const float* __restrict__ mv_w1, const float* __restrict__ gate_w1, const float* __restrict__ maa_w1,
    const float* __restrict__ dw2, const float* __restrict__ aaa_w2, const float* __restrict__ ma_w2,
    const float* __restrict__ kkk_w2, const float* __restrict__ mk_w2, const float* __restrict__ mv_w2,
    const float* __restrict__ gate_w2,
    bf16* __restrict__ PWwa, bf16* __restrict__ PWk, bf16* __restrict__ PWv,
    bf16* __restrict__ PWrg, bf16* __restrict__ PWmaa,
    bf16* __restrict__ W2wa, bf16* __restrict__ W2k, bf16* __restrict__ W2v, bf16* __restrict__ W2g){
  int idx = blockIdx.x*256 + threadIdx.x;
  if (idx < 491520) {
    int buf = idx / 98304, rem = idx - buf*98304;
    int n = rem / 768, kk = rem - n*768;
    float val = 0.f;
    bf16* dst;
    switch(buf){
      case 0: dst=PWwa; if(n<64) val=dw1[(size_t)kk*64+n]; else if(n<88) val=aaa_w1[(size_t)kk*24+(n-64)]; else if(n<112) val=ma_w1[(size_t)kk*24+(n-88)]; break;
      case 1: dst=PWk;  if(n<24) val=kkk_w1[(size_t)kk*24+n]; else if(n<48) val=mk_w1[(size_t)kk*24+(n-24)]; break;
      case 2: dst=PWv;  if(n<24) val=mv_w1[(size_t)kk*24+n]; break;
      case 3: dst=PWrg; if(n<120) val=gate_w1[(size_t)kk*120+n]; break;
      default: dst=PWmaa; if(n<112) val=maa_w1[(size_t)kk*112+n]; break;
    }
    dst[rem] = __float2bfloat16(val);
    return;
  }
  int i = idx - 491520;
  if (i < 294912){            // W2wa [2304][128]
    int n=i>>7, q=i&127, seg=n/768, c=n-seg*768;
    float val=0.f;
    if (seg==0){ if(q<64) val=dw2[(size_t)q*768+c]; }
    else if (seg==1){ if(q>=64&&q<88) val=aaa_w2[(size_t)(q-64)*768+c]; }
    else { if(q>=88&&q<112) val=ma_w2[(size_t)(q-88)*768+c]; }
    W2wa[i]=__float2bfloat16(val); return;
  }
  i -= 294912;
  if (i < 98304){             // W2k [1536][64]
    int n=i>>6, q=i&63, seg=n/768, c=n-seg*768;
    float val=0.f;
    if (seg==0){ if(q<24) val=kkk_w2[(size_t)q*768+c]; }
    else { if(q>=24&&q<48) val=mk_w2[(size_t)(q-24)*768+c]; }
    W2k[i]=__float2bfloat16(val); return;
  }
  i -= 98304;
  if (i < 24576){             // W2v [768][32]
    int c=i>>5, q=i&31;
    float val = (q<24) ? mv_w2[(size_t)q*768+c] : 0.f;
    W2v[i]=__float2bfloat16(val); return;
  }
  i -= 24576;
  if (i < 98304){             // W2g [768][128]
    int c=i>>7, q=i&127;
    float val = (q<120) ? gate_w2[(size_t)q*768+c] : 0.f;
    W2g[i]=__float2bfloat16(val);
  }
}

// ---------------- big bf16 MFMA GEMM, templated output dtype ----------------
template<typename OutT>
__global__ __launch_bounds__(256) void gemm_mfma(const bf16* __restrict__ A,
    const bf16* __restrict__ Bt, OutT* __restrict__ C, int M, int N, int K) {
  __shared__ unsigned short As[128*32];
  __shared__ unsigned short Bs[128*32];
  const int bm = blockIdx.y*128, bn = blockIdx.x*128;
  const int tid = threadIdx.x, lane = tid&63, w = tid>>6;
  const int wr = w>>1, wc = w&1;
  const int lr = lane&15, kg = lane>>4;
  f32x4 zero = {0.f,0.f,0.f,0.f};
  f32x4 acc[4][4];
  #pragma unroll
  for (int m=0;m<4;m++)
    #pragma unroll
    for (int n=0;n<4;n++) acc[m][n]=zero;
  const size_t rowA = (size_t)(bm + w*32 + (lane>>2))*K + (lane&3)*8;
  const size_t rowB = (size_t)(bn + w*32 + (lane>>2))*K + (lane&3)*8;
  unsigned short* lA = As + w*32*32;
  unsigned short* lB = Bs + w*32*32;
  for (int k0=0; k0<K; k0+=32){
    GLDS16(A + rowA + k0,                 lA);
    GLDS16(A + rowA + k0 + (size_t)16*K,  lA + 512);
    GLDS16(Bt + rowB + k0,                lB);
    GLDS16(Bt + rowB + k0 + (size_t)16*K, lB + 512);
    __syncthreads();
    bf16x8 af[4], bfr[4];
    #pragma unroll
    for (int m=0;m<4;m++) af[m]  = *(const bf16x8*)(void*)(As + (wr*64+m*16+lr)*32 + kg*8);
    #pragma unroll
    for (int n=0;n<4;n++) bfr[n] = *(const bf16x8*)(void*)(Bs + (wc*64+n*16+lr)*32 + kg*8);
    #pragma unroll
    for (int m=0;m<4;m++)
      #pragma unroll
      for (int n=0;n<4;n++)
        acc[m][n] = __builtin_amdgcn_mfma_f32_16x16x32_bf16(af[m], bfr[n], acc[m][n], 0,0,0);
    __syncthreads();
  }
  #pragma unroll
  for (int m=0;m<4;m++)
    #pragma unroll
    for (int n=0;n<4;n++){
      size_t r0 = (size_t)(bm + wr*64 + m*16 + kg*4);
      int cc = bn + wc*64 + n*16 + lr;
      #pragma unroll
      for (int q=0;q<4;q++){
        float val = acc[m][n][q];
        if constexpr (sizeof(OutT)==2) C[(r0+q)*N + cc] = __float2bfloat16(val);
        else                           C[(r0+q)*N + cc] = val;
      }
    }
}

// ---------------- gemm_tm: f32 out, N=112, tanh ----------------
__global__ __launch_bounds__(256) void gemm_tm(const bf16* __restrict__ A,
    const bf16* __restrict__ Bt, float* __restrict__ C, int K) {
  __shared__ unsigned short As[128*32];
  __shared__ unsigned short Bs[128*32];
  const int bm = blockIdx.y*128;
  const int tid = threadIdx.x, lane = tid&63, w = tid>>6;
  const int wr = w>>1, wc = w&1;
  const int lr = lane&15, kg = lane>>4;
  f32x4 zero = {0.f,0.f,0.f,0.f};
  f32x4 acc[4][4];
  #pragma unroll
  for (int m=0;m<4;m++)
    #pragma unroll
    for (int n=0;n<4;n++) acc[m][n]=zero;
  const size_t rowA = (size_t)(bm + w*32 + (lane>>2))*K + (lane&3)*8;
  const size_t rowB = (size_t)(w*32 + (lane>>2))*K + (lane&3)*8;
  unsigned short* lA = As + w*32*32;
  unsigned short* lB = Bs + w*32*32;
  for (int k0=0; k0<K; k0+=32){
    GLDS16(A + rowA + k0,                 lA);
    GLDS16(A + rowA + k0 + (size_t)16*K,  lA + 512);
    GLDS16(Bt + rowB + k0,                lB);
    GLDS16(Bt + rowB + k0 + (size_t)16*K, lB + 512);
    __syncthreads();
    bf16x8 af[4], bfr[4];
    #pragma unroll
    for (int m=0;m<4;m++) af[m]  = *(const bf16x8*)(void*)(As + (wr*64+m*16+lr)*32 + kg*8);
    #pragma unroll
    for (int n=0;n<4;n++) bfr[n] = *(const bf16x8*)(void*)(Bs + (wc*64+n*16+lr)*32 + kg*8);
    #pragma unroll
    for (int m=0;m<4;m++)
      #pragma unroll
      for (int n=0;n<4;n++)
        acc[m][n] = __builtin_amdgcn_mfma_f32_16x16x32_bf16(af[m], bfr[n], acc[m][n], 0,0,0);
    __syncthreads();
  }
  #pragma unroll
  for (int m=0;m<4;m++)
    #pragma unroll
    for (int n=0;n<4;n++){
      size_t r0 = (size_t)(bm + wr*64 + m*16 + kg*4);
      int cc = wc*64 + n*16 + lr;
      if (cc < 112){
        #pragma unroll
        for (int q=0;q<4;q++)
          C[(r0+q)*112 + cc] = tanhf(acc[m][n][q]);
      }
    }
}

// ---------------- stage-1 batched small GEMM -> bf16 padded, per-z activation ----------------
struct S1P {
  const bf16* A[4];
  const bf16* Bt[4];
  bf16* C[4];
  int Ntrue[4];
  int Nalloc[4];
  int act[4];
};
__global__ __launch_bounds__(256) void gemm_s1(S1P p, int K) {
  const int z = blockIdx.z;
  const bf16* __restrict__ A  = p.A[z];
  const bf16* __restrict__ Bt = p.Bt[z];
  bf16* __restrict__ C = p.C[z];
  const int Ntrue = p.Ntrue[z], Nalloc = p.Nalloc[z], act = p.act[z];
  __shared__ unsigned short As[128*32];
  __shared__ unsigned short Bs[128*32];
  const int bm = blockIdx.y*128;
  const int tid = threadIdx.x, lane = tid&63, w = tid>>6;
  const int wr = w>>1, wc = w&1;
  const int lr = lane&15, kg = lane>>4;
  f32x4 zero = {0.f,0.f,0.f,0.f};
  f32x4 acc[4][4];
  #pragma unroll
  for (int m=0;m<4;m++)
    #pragma unroll
    for (int n=0;n<4;n++) acc[m][n]=zero;
  const size_t rowA = (size_t)(bm + w*32 + (lane>>2))*K + (lane&3)*8;
  const size_t rowB = (size_t)(w*32 + (lane>>2))*K + (lane&3)*8;
  unsigned short* lA = As + w*32*32;
  unsigned short* lB = Bs + w*32*32;
  for (int k0=0; k0<K; k0+=32){
    GLDS16(A + rowA + k0,                 lA);
    GLDS16(A + rowA + k0 + (size_t)16*K,  lA + 512);
    GLDS16(Bt + rowB + k0,                lB);
    GLDS16(Bt + rowB + k0 + (size_t)16*K, lB + 512);
    __syncthreads();
    bf16x8 af[4], bfr[4];
    #pragma unroll
    for (int m=0;m<4;m++) af[m]  = *(const bf16x8*)(void*)(As + (wr*64+m*16+lr)*32 + kg*8);
    #pragma unroll
    for (int n=0;n<4;n++) bfr[n] = *(const bf16x8*)(void*)(Bs + (wc*64+n*16+lr)*32 + kg*8);
    #pragma unroll
    for (int m=0;m<4;m++)
      #pragma unroll
      for (int n=0;n<4;n++)
        acc[m][n] = __builtin_amdgcn_mfma_f32_16x16x32_bf16(af[m], bfr[n], acc[m][n], 0,0,0);
    __syncthreads();
  }
  #pragma unroll
  for (int m=0;m<4;m++)
    #pragma unroll
    for (int n=0;n<4;n++){
      size_t r0 = (size_t)(bm + wr*64 + m*16 + kg*4);
      int cc = wc*64 + n*16 + lr;
      if (cc < Nalloc){
        #pragma unroll
        for (int q=0;q<4;q++){
          float val = acc[m][n][q];
          if      (act==1){ if (cc<64) val = tanhf(val); }
          else if (act==2){ if (cc<24) val = tanhf(val); }
          else if (act==3){ val = sigm(val); }
          if (cc >= Ntrue) val = 0.f;
          C[(r0+q)*Nalloc + cc] = __float2bfloat16(val);
        }
      }
    }
}

// ---------------- stage-2 batched GEMM: z = h @ W2 -> bf16 ----------------
struct Z4 {
  const bf16* A[4];
  const bf16* Bt[4];
  bf16* C[4];
  int N[4];
  int K[4];
};
__global__ __launch_bounds__(256) void gemm_z(Z4 p) {
  const int z = blockIdx.z;
  const int N = p.N[z], K = p.K[z];
  const int bn = blockIdx.x*128;
  if (bn >= N) return;
  const bf16* __restrict__ A  = p.A[z];
  const bf16* __restrict__ Bt = p.Bt[z];
  bf16* __restrict__ C = p.C[z];
  __shared__ unsigned short As[128*32];
  __shared__ unsigned short Bs[128*32];
  const int bm = blockIdx.y*128;
  const int tid = threadIdx.x, lane = tid&63, w = tid>>6;
  const int wr = w>>1, wc = w&1;
  const int lr = lane&15, kg = lane>>4;
  f32x4 zero = {0.f,0.f,0.f,0.f};
  f32x4 acc[4][4];
  #pragma unroll
  for (int m=0;m<4;m++)
    #pragma unroll
    for (int n=0;n<4;n++) acc[m][n]=zero;
  const size_t rowA = (size_t)(bm + w*32 + (lane>>2))*K + (lane&3)*8;
  const size_t rowB = (size_t)(bn + w*32 + (lane>>2))*K + (lane&3)*8;
  unsigned short* lA = As + w*32*32;
  unsigned short* lB = Bs + w*32*32;
  for (int k0=0; k0<K; k0+=32){
    GLDS16(A + rowA + k0,                 lA);
    GLDS16(A + rowA + k0 + (size_t)16*K,  lA + 512);
    GLDS16(Bt + rowB + k0,                lB);
    GLDS16(Bt + rowB + k0 + (size_t)16*K, lB + 512);
    __syncthreads();
    bf16x8 af[4], bfr[4];
    #pragma unroll
    for (int m=0;m<4;m++) af[m]  = *(const bf16x8*)(void*)(As + (wr*64+m*16+lr)*32 + kg*8);
    #pragma unroll
    for (int n=0;n<4;n++) bfr[n] = *(const bf16x8*)(void*)(Bs + (wc*64+n*16+lr)*32 + kg*8);
    #pragma unroll
    for (int m=0;m<4;m++)
      #pragma unroll
      for (int n=0;n<4;n++)
        acc[m][n] = __builtin_amdgcn_mfma_f32_16x16x32_bf16(af[m], bfr[n], acc[m][n], 0,0,0);
    __syncthreads();
  }
  #pragma unroll
  for (int m=0;m<4;m++)
    #pragma unroll
    for (int n=0;n<4;n++){
      size_t r0 = (size_t)(bm + wr*64 + m*16 + kg*4);
      int cc = bn + wc*64 + n*16 + lr;
      #pragma unroll
      for (int q=0;q<4;q++)
        C[(r0+q)*N + cc] = __float2bfloat16(acc[m][n][q]);
    }
}

// ---------------- K2b: mix, 8 rows per block (tm pre-tanh'd) ----------------
__global__ __launch_bounds__(256) void k2_mix(const float* __restrict__ x, const float* __restrict__ xx,
    const float* __restrict__ tm, const float* __restrict__ w2,
    const float* __restrict__ mrg, const float* __restrict__ mwa,
    const float* __restrict__ mk_, const float* __restrict__ mv_,
    bf16* __restrict__ xrg, bf16* __restrict__ xwa, bf16* __restrict__ xk, bf16* __restrict__ xv) {
  const int row0 = blockIdx.x*8, tid = threadIdx.x;
  __shared__ float stm[8][112];
  for (int idx=tid; idx<8*112; idx+=256){
    int rr=idx/112, q=idx-rr*112;
    stm[rr][q]=tm[(size_t)(row0+rr)*112+q];
  }
  __syncthreads();
  for (int c=tid;c<Cdim;c+=256){
    float x8[8], d8[8];
    #pragma unroll
    for (int rr=0;rr<8;rr++){
      size_t i=(size_t)(row0+rr)*Cdim+c;
      x8[rr]=x[i]; d8[rr]=xx[i];
    }
    float mrgc=mrg[c], mwac=mwa[c], mkc=mk_[c], mvc=mv_[c];
    float m0[8]={},m1[8]={},m2[8]={},m3[8]={};
    #pragma unroll 4
    for (int d=0; d<28; d++){
      float w0=w2[(size_t)(d)*Cdim + c];
      float w1=w2[(size_t)(28+d)*Cdim + c];
      float w2v=w2[(size_t)(56+d)*Cdim + c];
      float w3=w2[(size_t)(84+d)*Cdim + c];
      #pragma unroll
      for (int rr=0;rr<8;rr++){
        m0[rr]+=stm[rr][d]*w0; m1[rr]+=stm[rr][28+d]*w1;
        m2[rr]+=stm[rr][56+d]*w2v; m3[rr]+=stm[rr][84+d]*w3;
      }
    }
    #pragma unroll
    for (int rr=0;rr<8;rr++){
      size_t i=(size_t)(row0+rr)*Cdim+c;
      xrg[i]=__float2bfloat16(x8[rr] + d8[rr]*(mrgc+m0[rr]));
      xwa[i]=__float2bfloat16(x8[rr] + d8[rr]*(mwac+m1[rr]));
      xk[i] =__float2bfloat16(x8[rr] + d8[rr]*(mkc+m2[rr]));
      xv[i] =__float2bfloat16(x8[rr] + d8[rr]*(mvc+m3[rr]));
    }
  }
}

// ---------------- K5 v3: pure elementwise + in-wave head norm ----------------
__global__ __launch_bounds__(256) void k5_fuse(
    const bf16* __restrict__ zwa, const bf16* __restrict__ zk, const bf16* __restrict__ zv,
    const float* __restrict__ td, const float* __restrict__ aaaaa,
    const float* __restrict__ misc_a, const float* __restrict__ misc_k, const float* __restrict__ misc_v,
    const float* __restrict__ v1,
    float* __restrict__ kbuf, float* __restrict__ vbuf, float* __restrict__ wexp,
    bf16* __restrict__ kb_bf, bf16* __restrict__ vb_bf,
    bf16* __restrict__ akv, bf16* __restrict__ bkv) {
  const int row = blockIdx.x, tid = threadIdx.x;
  float kraw[3], v0[3], v1v[3];
  #pragma unroll
  for (int it=0;it<3;it++){
    size_t i=(size_t)row*Cdim + tid + it*256;
    kraw[it]=kbuf[i]; v0[it]=vbuf[i]; v1v[it]=v1[i];
  }
  __syncthreads();   // all f32 reads of kbuf/vbuf done before bf16 overlay writes
  #pragma unroll
  for (int it=0;it<3;it++){
    const int c = tid + it*256;
    const size_t i=(size_t)row*Cdim+c;
    float zd = bf2f(zwa[(size_t)row*2304 + c]);
    float za = bf2f(zwa[(size_t)row*2304 + 768 + c]);
    float zma= bf2f(zwa[(size_t)row*2304 + 1536 + c]);
    float zkk= bf2f(zk[(size_t)row*1536 + c]);
    float zmk= bf2f(zk[(size_t)row*1536 + 768 + c]);
    float zmv= bf2f(zv[i]);
    float w = -softplusf(-(td[c]+zd)) - 0.5f;
    wexp[i] = expf(-expf(w));
    float a  = sigm(aaaaa[c]+za);
    float ma = sigm(misc_a[c]+zma);
    float mk = sigm(misc_k[c]+zmk);
    float mv = sigm(misc_v[c]+zmv);
    vb_bf[i] = __float2bfloat16(v0[it] + (v1v[it]-v0[it])*mv);
    float kf = kraw[it]*(ma + a*(1.f-ma))*expf(fminf(w*mk,0.f));
    kb_bf[i] = __float2bfloat16(kf);
    float kk = kraw[it] + zkk;
    float ss = red32(kk*kk);
    float kkn = kk * (1.f/fmaxf(sqrtf(ss),1e-12f));
    akv[i] = __float2bfloat16(-kkn);
    bkv[i] = __float2bfloat16(kkn*a);
  }
}

// ---------------- K6 v7: 8 single-wave blocks per head; wave = 4 rows x 16 lanes (2 elems/lane) ----------------
// Rows of S are independent given the shared per-step vectors -> split head over 8 blocks.
// bid mapping (head = bid % 192) keeps one head's 8 blocks on ONE XCD (round-robin dispatch, 192%8==0).
// Wave-private GLDS staging, raw vmcnt(0), register prefetch pipeline, all-DPP 16-lane reductions.
__global__ __launch_bounds__(64) void k6_wkv(const unsigned short* __restrict__ r, const float* __restrict__ wd,
    const unsigned short* __restrict__ k, const unsigned short* __restrict__ v,
    const unsigned short* __restrict__ a, const unsigned short* __restrict__ b2, float* __restrict__ y) {
  const int lane = threadIdx.x;
  const int bid = blockIdx.x;
  const int head = bid % (Bdim*Hdim);        // 0..191
  const int rq   = bid / (Bdim*Hdim);        // 0..7 (row quad)
  const int bb = head / Hdim, hh = head - bb*Hdim;
  const int rl = lane >> 4;                  // local row 0..3
  const int i0 = rq*4 + rl;                  // global row 0..31
  const int jh = lane & 15;                  // 16 lanes per row
  const int col = jh*2;                      // owns j = col, col+1
  __shared__ __align__(16) float swd[2][CH6][Ndim];               // 4 KB
  __shared__ __align__(16) unsigned short sbf[2][4][CH6][Ndim];   // r,k,a,b : 8 KB
  __shared__ __align__(16) unsigned short sv2[2][CH6][Ndim];      // v : 2 KB
  const unsigned short* gb16[4] = {r, k, a, b2};
  const size_t gbase = (size_t)bb*Tdim*Cdim + (size_t)hh*Ndim;
  float S0=0.f, S1=0.f;

  auto STAGE = [&](int c, int buf){
    const size_t tb = (size_t)c*CH6;
    GLDS16(wd + gbase + (tb +   (lane>>3))*Cdim + (lane&7)*4, &swd[buf][0][0]);
    GLDS16(wd + gbase + (tb + 8+(lane>>3))*Cdim + (lane&7)*4, &swd[buf][8][0]);
    #pragma unroll
    for (int arr=0; arr<4; arr++)
      GLDS16(gb16[arr] + gbase + (tb + (lane>>2))*Cdim + (lane&3)*8, &sbf[buf][arr][0][0]);
    GLDS16(v + gbase + (tb + (lane>>2))*Cdim + (lane&3)*8, &sv2[buf][0][0]);
  };

  unsigned nr, nk, na, nb; float2 nw; unsigned short nv;
  auto LOADT = [&](int buf, int t){
    nr = *(const unsigned*)&sbf[buf][0][t][col];
    nk = *(const unsigned*)&sbf[buf][1][t][col];
    na = *(const unsigned*)&sbf[buf][2][t][col];
    nb = *(const unsigned*)&sbf[buf][3][t][col];
    nw = *(const float2*)&swd[buf][t][col];
    nv = sv2[buf][t][i0];
  };

  STAGE(0, 0);
  asm volatile("s_waitcnt vmcnt(0)" ::: "memory");
  LOADT(0, 0);
  int buf = 0;
  const int NCH = Tdim/CH6;
  for (int c=0; c<NCH; ++c){
    if (c+1 < NCH) STAGE(c+1, buf^1);
    const size_t yb = gbase + (size_t)c*CH6*Cdim;
    #pragma unroll
    for (int t=0; t<CH6; t++){
      unsigned cr=nr, ck=nk, ca=na, cb=nb;
      float2 cw=nw;
      unsigned short cv=nv;
      if (t < CH6-1) LOADT(buf, t+1);       // prefetch next step (raw)
      float a0 = __builtin_bit_cast(float, ca<<16);
      float a1 = __builtin_bit_cast(float, ca&0xFFFF0000u);
      float sa = S0*a0 + S1*a1;
      sa = red16(sa);
      float k0 = __builtin_bit_cast(float, ck<<16);
      float k1 = __builtin_bit_cast(float, ck&0xFFFF0000u);
      float b0 = __builtin_bit_cast(float, cb<<16);
      float b1 = __builtin_bit_cast(float, cb&0xFFFF0000u);
      float r0 = __builtin_bit_cast(float, cr<<16);
      float r1 = __builtin_bit_cast(float, cr&0xFFFF0000u);
      const float vl = us2f(cv);
      S0 = S0*cw.x + (sa*b0 + vl*k0);
      S1 = S1*cw.y + (sa*b1 + vl*k1);
      float yv = S0*r0 + S1*r1;
      yv = red16(yv);
      if (jh == 0) y[yb + (size_t)t*Cdim + i0] = yv;
      if (t == CH6-1 && c+1 < NCH){
        asm volatile("s_waitcnt vmcnt(0)" ::: "memory");
        LOADT(buf^1, 0);                    // first step of next chunk
      }
    }
    buf ^= 1;
  }
}

// ---------------- K7 v3: GroupNorm + bonus + gate (bf16 inputs) ----------------
__global__ __launch_bounds__(256) void k7_post(const float* __restrict__ y,
    const bf16* __restrict__ r, const bf16* __restrict__ kf, const bf16* __restrict__ v,
    const bf16* __restrict__ g, const float* __restrict__ faaaa,
    const float* __restrict__ lnw, const float* __restrict__ lnb,
    bf16* __restrict__ ygate) {
  const int row = blockIdx.x, tid = threadIdx.x;
  #pragma unroll
  for (int it=0; it<3; it++){
    const int c = tid + it*256;
    const size_t i = (size_t)row*Cdim + c;
    float yv = y[i];
    float bon = bf2f(r[i])*bf2f(kf[i])*faaaa[c];
    float s  = red32(yv);
    float ss = red32(yv*yv);
    float bn = red32(bon);
    float mu = s*(1.f/Ndim);
    float var = ss*(1.f/Ndim) - mu*mu;
    float rs = rsqrtf(var + 6.4e-5f);
    float yn = (yv-mu)*rs*lnw[c]+lnb[c];
    ygate[i]=__float2bfloat16((yn + bn*bf2f(v[i]))*bf2f(g[i]));
  }
}

// ---------------- K9: v1 passthrough (float4) ----------------
__global__ void k9_copy(const float4* __restrict__ src, float4* __restrict__ dst){
  int idx = blockIdx.x*256 + threadIdx.x;
  if (idx < BTdim*Cdim/4) dst[idx]=src[idx];
}

extern "C" void kernel_launch(void* const* d_in, const int* in_sizes, int n_in,
                              void* d_out, int out_size, void* d_ws, size_t ws_size,
                              hipStream_t stream) {
  const float* x      = (const float*)d_in[0];
  const float* v1     = (const float*)d_in[1];
  const float* maa_x  = (const float*)d_in[2];
  const float* maa_rg = (const float*)d_in[3];
  const float* maa_wa = (const float*)d_in[4];
  const float* maa_k  = (const float*)d_in[5];
  const float* maa_v  = (const float*)d_in[6];
  const float* time_decay = (const float*)d_in[7];
  const float* faaaa  = (const float*)d_in[8];
  const float* aaaaa  = (const float*)d_in[9];
  const float* maa_w1 = (const float*)d_in[10];
  const float* maa_w2 = (const float*)d_in[11];
  const float* dw1    = (const float*)d_in[12];
  const float* dw2    = (const float*)d_in[13];
  const float* aaa_w1 = (const float*)d_in[14];
  const float* aaa_w2 = (const float*)d_in[15];
  const float* kkk_w1 = (const float*)d_in[16];
  const float* kkk_w2 = (const float*)d_in[17];
  const float* gate_w1= (const float*)d_in[18];
  const float* gate_w2= (const float*)d_in[19];
  const float* ma_w1  = (const float*)d_in[20];
  const float* ma_w2  = (const float*)d_in[21];
  const float* misc_a = (const float*)d_in[22];
  const float* mk_w1  = (const float*)d_in[23];
  const float* mk_w2  = (const float*)d_in[24];
  const float* misc_k = (const float*)d_in[25];
  const float* mv_w1  = (const float*)d_in[26];
  const float* mv_w2  = (const float*)d_in[27];
  const float* misc_v = (const float*)d_in[28];
  const float* Wr     = (const float*)d_in[29];
  const float* Wk     = (const float*)d_in[30];
  const float* Wv     = (const float*)d_in[31];
  const float* Wo     = (const float*)d_in[32];
  const float* lnw    = (const float*)d_in[33];
  const float* lnb    = (const float*)d_in[34];
  float* out = (float*)d_out;

  float* ws = (float*)d_ws;
  const size_t BTC = (size_t)BTdim*Cdim;   // 6291456
  const size_t HB  = BTC/2;                // 3145728
  float* xx   = ws;                float* wexp = ws;
  float* kb   = ws + 2*HB;         bf16* kb_bf = (bf16*)kb;
  float* vb   = ws + 4*HB;         bf16* vb_bf = (bf16*)vb;
  bf16* xrg_bf = (bf16*)(ws + 6*HB);
  bf16* xwa_bf = xrg_bf + BTC;
  bf16* zwa_bf = (bf16*)(ws + 6*HB);
  bf16* xk_bf  = (bf16*)(ws + 9*HB);
  bf16* xv_bf  = xk_bf + BTC;
  bf16* zk_bf  = (bf16*)(ws + 9*HB);
  bf16* xxx_bf = (bf16*)(ws + 11*HB);
  bf16* zv_bf  = (bf16*)(ws + 11*HB);
  float* tm    = ws + 12*HB;
  bf16* zg_bf  = (bf16*)(ws + 12*HB);
  bf16* hwa_bf = (bf16*)(ws + 13*HB);
  bf16* hk_bf  = hwa_bf + (size_t)BTdim*128;
  bf16* hv_bf  = hk_bf  + (size_t)BTdim*64;
  bf16* hrg_bf = hv_bf  + (size_t)BTdim*32;
  bf16* akv_bf = (bf16*)(ws + 13*HB);
  bf16* bkv_bf = (bf16*)(ws + 14*HB);
  bf16* yg_bf  = (bf16*)(ws + 14*HB);
  float* ybuf  = ws + 15*HB;
  bf16* rb_bf  = (bf16*)(ws + 17*HB);
  bf16* Wbase  = (bf16*)(ws + 18*HB);
  bf16* WtR = Wbase;
  bf16* WtK = WtR + 589824;
  bf16* WtV = WtK + 589824;
  bf16* WtO = WtV + 589824;
  bf16* PWwa = WtO + 589824;
  bf16* PWk  = PWwa + 98304;
  bf16* PWv  = PWk  + 98304;
  bf16* PWrg = PWv  + 98304;
  bf16* PWmaa= PWrg + 98304;
  bf16* W2wa = PWmaa + 98304;
  bf16* W2k  = W2wa + 294912;
  bf16* W2v  = W2k  + 98304;
  bf16* W2g  = W2v  + 24576;

  dim3 blk(256);
  kconvW<<<dim3(24,24,4), blk, 0, stream>>>(Wr,Wk,Wv,Wo, WtR,WtK,WtV,WtO);
  kprep<<<dim3(3936), blk, 0, stream>>>(dw1,aaa_w1,ma_w1,kkk_w1,mk_w1,mv_w1,gate_w1,maa_w1,
                                        dw2,aaa_w2,ma_w2,kkk_w2,mk_w2,mv_w2,gate_w2,
                                        PWwa,PWk,PWv,PWrg,PWmaa, W2wa,W2k,W2v,W2g);
  k1_shift<<<dim3((BTdim*Cdim+255)/256), blk, 0, stream>>>(x, maa_x, xx, xxx_bf);
  gemm_tm<<<dim3(1,64), blk, 0, stream>>>(xxx_bf, PWmaa, tm, Cdim);
  k2_mix<<<dim3(BTdim/8), blk, 0, stream>>>(x, xx, tm, maa_w2, maa_rg, maa_wa, maa_k, maa_v,
                                            xrg_bf, xwa_bf, xk_bf, xv_bf);
  {
    S1P p{};
    p.A[0]=xwa_bf; p.Bt[0]=PWwa; p.C[0]=hwa_bf; p.Ntrue[0]=112; p.Nalloc[0]=128; p.act[0]=1;
    p.A[1]=xk_bf;  p.Bt[1]=PWk;  p.C[1]=hk_bf;  p.Ntrue[1]=48;  p.Nalloc[1]=64;  p.act[1]=2;
    p.A[2]=xv_bf;  p.Bt[2]=PWv;  p.C[2]=hv_bf;  p.Ntrue[2]=24;  p.Nalloc[2]=32;  p.act[2]=0;
    p.A[3]=xrg_bf; p.Bt[3]=PWrg; p.C[3]=hrg_bf; p.Ntrue[3]=120; p.Nalloc[3]=128; p.act[3]=3;
    gemm_s1<<<dim3(1,64,4), blk, 0, stream>>>(p, Cdim);
  }
  gemm_mfma<bf16> <<<dim3(6,64), blk, 0, stream>>>(xrg_bf, WtR, rb_bf, BTdim, Cdim, Cdim);
  gemm_mfma<float><<<dim3(6,64), blk, 0, stream>>>(xk_bf,  WtK, kb,    BTdim, Cdim, Cdim);
  gemm_mfma<float><<<dim3(6,64), blk, 0, stream>>>(xv_bf,  WtV, vb,    BTdim, Cdim, Cdim);
  {
    Z4 p{};
    p.A[0]=hwa_bf; p.Bt[0]=W2wa; p.C[0]=zwa_bf; p.N[0]=2304; p.K[0]=128;
    p.A[1]=hk_bf;  p.Bt[1]=W2k;  p.C[1]=zk_bf;  p.N[1]=1536; p.K[1]=64;
    p.A[2]=hv_bf;  p.Bt[2]=W2v;  p.C[2]=zv_bf;  p.N[2]=768;  p.K[2]=32;
    p.A[3]=hrg_bf; p.Bt[3]=W2g;  p.C[3]=zg_bf;  p.N[3]=768;  p.K[3]=128;
    gemm_z<<<dim3(18,64,4), blk, 0, stream>>>(p);
  }
  k5_fuse<<<dim3(BTdim), blk, 0, stream>>>(zwa_bf, zk_bf, zv_bf,
      time_decay, aaaaa, misc_a, misc_k, misc_v, v1,
      kb, vb, wexp, kb_bf, vb_bf, akv_bf, bkv_bf);
  k6_wkv<<<dim3(Bdim*Hdim*8), dim3(64), 0, stream>>>((const unsigned short*)rb_bf, wexp,
      (const unsigned short*)kb_bf, (const unsigned short*)vb_bf,
      (const unsigned short*)akv_bf, (const unsigned short*)bkv_bf, ybuf);
  k7_post<<<dim3(BTdim), blk, 0, stream>>>(ybuf, rb_bf, kb_bf, vb_bf, zg_bf, faaaa, lnw, lnb, yg_bf);
  gemm_mfma<float><<<dim3(6,64), blk, 0, stream>>>(yg_bf, WtO, out, BTdim, Cdim, Cdim);
  k9_copy<<<dim3(BTdim*Cdim/4/256), blk, 0, stream>>>((const float4*)v1, (float4*)(out + BTC));
}

// Round 9
// 527.083 us; speedup vs baseline: 1.9369x; 1.0211x over previous
//
#include <hip/hip_runtime.h>
#include <hip/hip_bf16.h>
#include <math.h>

#define Bdim 8
#define Tdim 1024
#define Cdim 768
#define Hdim 24
#define Ndim 32
#define BTdim (Bdim*Tdim)
#define CH6 16

typedef __attribute__((ext_vector_type(8))) short bf16x8;
typedef __attribute__((ext_vector_type(4))) float f32x4;
typedef __hip_bfloat16 bf16;

__device__ __forceinline__ float sigm(float x){ return 1.f/(1.f+expf(-x)); }
__device__ __forceinline__ float softplusf(float x){ return fmaxf(x,0.f) + log1pf(expf(-fabsf(x))); }
__device__ __forceinline__ float bf2f(bf16 v){ return __bfloat162float(v); }
__device__ __forceinline__ float us2f(unsigned short s){ return __builtin_bit_cast(float, (unsigned)s<<16); }

template<int CTRL>
__device__ __forceinline__ float dpp_add(float x){
  int xi = __builtin_bit_cast(int, x);
  int yi = __builtin_amdgcn_mov_dpp(xi, CTRL, 0xF, 0xF, true);
  return x + __builtin_bit_cast(float, yi);
}
__device__ __forceinline__ float red32(float x){
  x = dpp_add<0xB1>(x);
  x = dpp_add<0x4E>(x);
  x = dpp_add<0x141>(x);
  x = dpp_add<0x140>(x);
  x += __shfl_xor(x, 16);
  return x;
}
// sum over each 16-lane row (all lanes receive the result)
__device__ __forceinline__ float red16(float x){
  x = dpp_add<0xB1>(x);
  x = dpp_add<0x4E>(x);
  x = dpp_add<0x141>(x);
  x = dpp_add<0x140>(x);
  return x;
}

#define GLDS16(gp, lp) __builtin_amdgcn_global_load_lds((const __attribute__((address_space(1))) void*)(gp), (__attribute__((address_space(3))) void*)(lp), 16, 0, 0)

// ---------------- K1: token shift ----------------
__global__ void k1_shift(const float* __restrict__ x, const float* __restrict__ maa_x,
                         float* __restrict__ xx, bf16* __restrict__ xxx) {
  int idx = blockIdx.x*256 + threadIdx.x;
  if (idx >= BTdim*Cdim) return;
  int c = idx % Cdim; int row = idx / Cdim; int t = row % Tdim;
  float xv = x[idx];
  float xp = (t==0) ? 0.f : x[idx - Cdim];
  float d = xp - xv;
  xx[idx] = d;
  xxx[idx] = __float2bfloat16(xv + d*maa_x[c]);
}

// ---------------- big weight convert + transpose ----------------
__global__ __launch_bounds__(256) void kconvW(const float* __restrict__ W0, const float* __restrict__ W1,
    const float* __restrict__ W2, const float* __restrict__ W3,
    bf16* __restrict__ T0, bf16* __restrict__ T1, bf16* __restrict__ T2, bf16* __restrict__ T3) {
  const float* Wsrc[4] = {W0,W1,W2,W3};
  bf16* Tdst[4] = {T0,T1,T2,T3};
  const float* W = Wsrc[blockIdx.z];
  bf16* T = Tdst[blockIdx.z];
  __shared__ float tile[32][33];
  int bx = blockIdx.x*32, by = blockIdx.y*32;
  int tx = threadIdx.x & 31, ty = threadIdx.x >> 5;
  #pragma unroll
  for (int q=0;q<32;q+=8) tile[ty+q][tx] = W[(size_t)(by+ty+q)*Cdim + bx+tx];
  __syncthreads();
  #pragma unroll
  for (int q=0;q<32;q+=8) T[(size_t)(bx+ty+q)*Cdim + by+tx] = __float2bfloat16(tile[tx][ty+q]);
}

// ---------------- pack stage-1 and stage-2 small weights (transposed bf16, zero-padded) ----------------
__global__ __launch_bounds__(256) void kprep(const float* __restrict__ dw1, const float* __restrict__ aaa_w1,
    const float* __restrict__ ma_w1, const float* __restrict__ kkk_w1, const float* __restrict__ mk_w1,
    const float* __restrict__ mv_w1, const float* __restrict__ gate_w1, const float* __restrict__ maa_w1,
    const float* __restrict__ dw2, const float* __restrict__ aaa_w2, const float* __restrict__ ma_w2,
    const float* __restrict__ kkk_w2, const float* __restrict__ mk_w2, const float* __restrict__ mv_w2,
    const float* __restrict__ gate_w2,
    bf16* __restrict__ PWwa, bf16* __restrict__ PWk, bf16* __restrict__ PWv,
    bf16* __restrict__ PWrg, bf16* __restrict__ PWmaa,
    bf16* __restrict__ W2wa, bf16* __restrict__ W2k, bf16* __restrict__ W2v, bf16* __restrict__ W2g){
  int idx = blockIdx.x*256 + threadIdx.x;
  if (idx < 491520) {
    int buf = idx / 98304, rem = idx - buf*98304;
    int n = rem / 768, kk = rem - n*768;
    float val = 0.f;
    bf16* dst;
    switch(buf){
      case 0: dst=PWwa; if(n<64) val=dw1[(size_t)kk*64+n]; else if(n<88) val=aaa_w1[(size_t)kk*24+(n-64)]; else if(n<112) val=ma_w1[(size_t)kk*24+(n-88)]; break;
      case 1: dst=PWk;  if(n<24) val=kkk_w1[(size_t)kk*24+n]; else if(n<48) val=mk_w1[(size_t)kk*24+(n-24)]; break;
      case 2: dst=PWv;  if(n<24) val=mv_w1[(size_t)kk*24+n]; break;
      case 3: dst=PWrg; if(n<120) val=gate_w1[(size_t)kk*120+n]; break;
      default: dst=PWmaa; if(n<112) val=maa_w1[(size_t)kk*112+n]; break;
    }
    dst[rem] = __float2bfloat16(val);
    return;
  }
  int i = idx - 491520;
  if (i < 294912){            // W2wa [2304][128]
    int n=i>>7, q=i&127, seg=n/768, c=n-seg*768;
    float val=0.f;
    if (seg==0){ if(q<64) val=dw2[(size_t)q*768+c]; }
    else if (seg==1){ if(q>=64&&q<88) val=aaa_w2[(size_t)(q-64)*768+c]; }
    else { if(q>=88&&q<112) val=ma_w2[(size_t)(q-88)*768+c]; }
    W2wa[i]=__float2bfloat16(val); return;
  }
  i -= 294912;
  if (i < 98304){             // W2k [1536][64]
    int n=i>>6, q=i&63, seg=n/768, c=n-seg*768;
    float val=0.f;
    if (seg==0){ if(q<24) val=kkk_w2[(size_t)q*768+c]; }
    else { if(q>=24&&q<48) val=mk_w2[(size_t)(q-24)*768+c]; }
    W2k[i]=__float2bfloat16(val); return;
  }
  i -= 98304;
  if (i < 24576){             // W2v [768][32]
    int c=i>>5, q=i&31;
    float val = (q<24) ? mv_w2[(size_t)q*768+c] : 0.f;
    W2v[i]=__float2bfloat16(val); return;
  }
  i -= 24576;
  if (i < 98304){             // W2g [768][128]
    int c=i>>7, q=i&127;
    float val = (q<120) ? gate_w2[(size_t)q*768+c] : 0.f;
    W2g[i]=__float2bfloat16(val);
  }
}

// ---------------- big bf16 MFMA GEMM (single), f32 out (Wo) ----------------
__global__ __launch_bounds__(256) void gemm_mfma(const bf16* __restrict__ A,
    const bf16* __restrict__ Bt, float* __restrict__ C, int M, int N, int K) {
  __shared__ unsigned short As[128*32];
  __shared__ unsigned short Bs[128*32];
  const int bm = blockIdx.y*128, bn = blockIdx.x*128;
  const int tid = threadIdx.x, lane = tid&63, w = tid>>6;
  const int wr = w>>1, wc = w&1;
  const int lr = lane&15, kg = lane>>4;
  f32x4 zero = {0.f,0.f,0.f,0.f};
  f32x4 acc[4][4];
  #pragma unroll
  for (int m=0;m<4;m++)
    #pragma unroll
    for (int n=0;n<4;n++) acc[m][n]=zero;
  const size_t rowA = (size_t)(bm + w*32 + (lane>>2))*K + (lane&3)*8;
  const size_t rowB = (size_t)(bn + w*32 + (lane>>2))*K + (lane&3)*8;
  unsigned short* lA = As + w*32*32;
  unsigned short* lB = Bs + w*32*32;
  for (int k0=0; k0<K; k0+=32){
    GLDS16(A + rowA + k0,                 lA);
    GLDS16(A + rowA + k0 + (size_t)16*K,  lA + 512);
    GLDS16(Bt + rowB + k0,                lB);
    GLDS16(Bt + rowB + k0 + (size_t)16*K, lB + 512);
    __syncthreads();
    bf16x8 af[4], bfr[4];
    #pragma unroll
    for (int m=0;m<4;m++) af[m]  = *(const bf16x8*)(void*)(As + (wr*64+m*16+lr)*32 + kg*8);
    #pragma unroll
    for (int n=0;n<4;n++) bfr[n] = *(const bf16x8*)(void*)(Bs + (wc*64+n*16+lr)*32 + kg*8);
    #pragma unroll
    for (int m=0;m<4;m++)
      #pragma unroll
      for (int n=0;n<4;n++)
        acc[m][n] = __builtin_amdgcn_mfma_f32_16x16x32_bf16(af[m], bfr[n], acc[m][n], 0,0,0);
    __syncthreads();
  }
  #pragma unroll
  for (int m=0;m<4;m++)
    #pragma unroll
    for (int n=0;n<4;n++){
      size_t r0 = (size_t)(bm + wr*64 + m*16 + kg*4);
      int cc = bn + wc*64 + n*16 + lr;
      #pragma unroll
      for (int q=0;q<4;q++)
        C[(r0+q)*N + cc] = acc[m][n][q];
    }
}

// ---------------- batched big GEMMs (r/k/v), per-z output dtype ----------------
struct G3 {
  const bf16* A[3];
  const bf16* Bt[3];
  float* Cf[3];
  bf16* Ch[3];
  int isbf[3];
};
__global__ __launch_bounds__(256) void gemm_big3(G3 p, int N, int K) {
  const int z = blockIdx.z;
  const bf16* __restrict__ A  = p.A[z];
  const bf16* __restrict__ Bt = p.Bt[z];
  const int isbf = p.isbf[z];
  __shared__ unsigned short As[128*32];
  __shared__ unsigned short Bs[128*32];
  const int bm = blockIdx.y*128, bn = blockIdx.x*128;
  const int tid = threadIdx.x, lane = tid&63, w = tid>>6;
  const int wr = w>>1, wc = w&1;
  const int lr = lane&15, kg = lane>>4;
  f32x4 zero = {0.f,0.f,0.f,0.f};
  f32x4 acc[4][4];
  #pragma unroll
  for (int m=0;m<4;m++)
    #pragma unroll
    for (int n=0;n<4;n++) acc[m][n]=zero;
  const size_t rowA = (size_t)(bm + w*32 + (lane>>2))*K + (lane&3)*8;
  const size_t rowB = (size_t)(bn + w*32 + (lane>>2))*K + (lane&3)*8;
  unsigned short* lA = As + w*32*32;
  unsigned short* lB = Bs + w*32*32;
  for (int k0=0; k0<K; k0+=32){
    GLDS16(A + rowA + k0,                 lA);
    GLDS16(A + rowA + k0 + (size_t)16*K,  lA + 512);
    GLDS16(Bt + rowB + k0,                lB);
    GLDS16(Bt + rowB + k0 + (size_t)16*K, lB + 512);
    __syncthreads();
    bf16x8 af[4], bfr[4];
    #pragma unroll
    for (int m=0;m<4;m++) af[m]  = *(const bf16x8*)(void*)(As + (wr*64+m*16+lr)*32 + kg*8);
    #pragma unroll
    for (int n=0;n<4;n++) bfr[n] = *(const bf16x8*)(void*)(Bs + (wc*64+n*16+lr)*32 + kg*8);
    #pragma unroll
    for (int m=0;m<4;m++)
      #pragma unroll
      for (int n=0;n<4;n++)
        acc[m][n] = __builtin_amdgcn_mfma_f32_16x16x32_bf16(af[m], bfr[n], acc[m][n], 0,0,0);
    __syncthreads();
  }
  if (isbf){
    bf16* __restrict__ C = p.Ch[z];
    #pragma unroll
    for (int m=0;m<4;m++)
      #pragma unroll
      for (int n=0;n<4;n++){
        size_t r0 = (size_t)(bm + wr*64 + m*16 + kg*4);
        int cc = bn + wc*64 + n*16 + lr;
        #pragma unroll
        for (int q=0;q<4;q++)
          C[(r0+q)*N + cc] = __float2bfloat16(acc[m][n][q]);
      }
  } else {
    float* __restrict__ C = p.Cf[z];
    #pragma unroll
    for (int m=0;m<4;m++)
      #pragma unroll
      for (int n=0;n<4;n++){
        size_t r0 = (size_t)(bm + wr*64 + m*16 + kg*4);
        int cc = bn + wc*64 + n*16 + lr;
        #pragma unroll
        for (int q=0;q<4;q++)
          C[(r0+q)*N + cc] = acc[m][n][q];
      }
  }
}

// ---------------- gemm_tm: f32 out, N=112, tanh ----------------
__global__ __launch_bounds__(256) void gemm_tm(const bf16* __restrict__ A,
    const bf16* __restrict__ Bt, float* __restrict__ C, int K) {
  __shared__ unsigned short As[128*32];
  __shared__ unsigned short Bs[128*32];
  const int bm = blockIdx.y*128;
  const int tid = threadIdx.x, lane = tid&63, w = tid>>6;
  const int wr = w>>1, wc = w&1;
  const int lr = lane&15, kg = lane>>4;
  f32x4 zero = {0.f,0.f,0.f,0.f};
  f32x4 acc[4][4];
  #pragma unroll
  for (int m=0;m<4;m++)
    #pragma unroll
    for (int n=0;n<4;n++) acc[m][n]=zero;
  const size_t rowA = (size_t)(bm + w*32 + (lane>>2))*K + (lane&3)*8;
  const size_t rowB = (size_t)(w*32 + (lane>>2))*K + (lane&3)*8;
  unsigned short* lA = As + w*32*32;
  unsigned short* lB = Bs + w*32*32;
  for (int k0=0; k0<K; k0+=32){
    GLDS16(A + rowA + k0,                 lA);
    GLDS16(A + rowA + k0 + (size_t)16*K,  lA + 512);
    GLDS16(Bt + rowB + k0,                lB);
    GLDS16(Bt + rowB + k0 + (size_t)16*K, lB + 512);
    __syncthreads();
    bf16x8 af[4], bfr[4];
    #pragma unroll
    for (int m=0;m<4;m++) af[m]  = *(const bf16x8*)(void*)(As + (wr*64+m*16+lr)*32 + kg*8);
    #pragma unroll
    for (int n=0;n<4;n++) bfr[n] = *(const bf16x8*)(void*)(Bs + (wc*64+n*16+lr)*32 + kg*8);
    #pragma unroll
    for (int m=0;m<4;m++)
      #pragma unroll
      for (int n=0;n<4;n++)
        acc[m][n] = __builtin_amdgcn_mfma_f32_16x16x32_bf16(af[m], bfr[n], acc[m][n], 0,0,0);
    __syncthreads();
  }
  #pragma unroll
  for (int m=0;m<4;m++)
    #pragma unroll
    for (int n=0;n<4;n++){
      size_t r0 = (size_t)(bm + wr*64 + m*16 + kg*4);
      int cc = wc*64 + n*16 + lr;
      if (cc < 112){
        #pragma unroll
        for (int q=0;q<4;q++)
          C[(r0+q)*112 + cc] = tanhf(acc[m][n][q]);
      }
    }
}

// ---------------- stage-1 batched small GEMM -> bf16 padded, per-z activation ----------------
struct S1P {
  const bf16* A[4];
  const bf16* Bt[4];
  bf16* C[4];
  int Ntrue[4];
  int Nalloc[4];
  int act[4];
};
__global__ __launch_bounds__(256) void gemm_s1(S1P p, int K) {
  const int z = blockIdx.z;
  const bf16* __restrict__ A  = p.A[z];
  const bf16* __restrict__ Bt = p.Bt[z];
  bf16* __restrict__ C = p.C[z];
  const int Ntrue = p.Ntrue[z], Nalloc = p.Nalloc[z], act = p.act[z];
  __shared__ unsigned short As[128*32];
  __shared__ unsigned short Bs[128*32];
  const int bm = blockIdx.y*128;
  const int tid = threadIdx.x, lane = tid&63, w = tid>>6;
  const int wr = w>>1, wc = w&1;
  const int lr = lane&15, kg = lane>>4;
  f32x4 zero = {0.f,0.f,0.f,0.f};
  f32x4 acc[4][4];
  #pragma unroll
  for (int m=0;m<4;m++)
    #pragma unroll
    for (int n=0;n<4;n++) acc[m][n]=zero;
  const size_t rowA = (size_t)(bm + w*32 + (lane>>2))*K + (lane&3)*8;
  const size_t rowB = (size_t)(w*32 + (lane>>2))*K + (lane&3)*8;
  unsigned short* lA = As + w*32*32;
  unsigned short* lB = Bs + w*32*32;
  for (int k0=0; k0<K; k0+=32){
    GLDS16(A + rowA + k0,                 lA);
    GLDS16(A + rowA + k0 + (size_t)16*K,  lA + 512);
    GLDS16(Bt + rowB + k0,                lB);
    GLDS16(Bt + rowB + k0 + (size_t)16*K, lB + 512);
    __syncthreads();
    bf16x8 af[4], bfr[4];
    #pragma unroll
    for (int m=0;m<4;m++) af[m]  = *(const bf16x8*)(void*)(As + (wr*64+m*16+lr)*32 + kg*8);
    #pragma unroll
    for (int n=0;n<4;n++) bfr[n] = *(const bf16x8*)(void*)(Bs + (wc*64+n*16+lr)*32 + kg*8);
    #pragma unroll
    for (int m=0;m<4;m++)
      #pragma unroll
      for (int n=0;n<4;n++)
        acc[m][n] = __builtin_amdgcn_mfma_f32_16x16x32_bf16(af[m], bfr[n], acc[m][n], 0,0,0);
    __syncthreads();
  }
  #pragma unroll
  for (int m=0;m<4;m++)
    #pragma unroll
    for (int n=0;n<4;n++){
      size_t r0 = (size_t)(bm + wr*64 + m*16 + kg*4);
      int cc = wc*64 + n*16 + lr;
      if (cc < Nalloc){
        #pragma unroll
        for (int q=0;q<4;q++){
          float val = acc[m][n][q];
          if      (act==1){ if (cc<64) val = tanhf(val); }
          else if (act==2){ if (cc<24) val = tanhf(val); }
          else if (act==3){ val = sigm(val); }
          if (cc >= Ntrue) val = 0.f;
          C[(r0+q)*Nalloc + cc] = __float2bfloat16(val);
        }
      }
    }
}

// ---------------- stage-2 batched GEMM: z = h @ W2 -> bf16 ----------------
struct Z4 {
  const bf16* A[4];
  const bf16* Bt[4];
  bf16* C[4];
  int N[4];
  int K[4];
};
__global__ __launch_bounds__(256) void gemm_z(Z4 p) {
  const int z = blockIdx.z;
  const int N = p.N[z], K = p.K[z];
  const int bn = blockIdx.x*128;
  if (bn >= N) return;
  const bf16* __restrict__ A  = p.A[z];
  const bf16* __restrict__ Bt = p.Bt[z];
  bf16* __restrict__ C = p.C[z];
  __shared__ unsigned short As[128*32];
  __shared__ unsigned short Bs[128*32];
  const int bm = blockIdx.y*128;
  const int tid = threadIdx.x, lane = tid&63, w = tid>>6;
  const int wr = w>>1, wc = w&1;
  const int lr = lane&15, kg = lane>>4;
  f32x4 zero = {0.f,0.f,0.f,0.f};
  f32x4 acc[4][4];
  #pragma unroll
  for (int m=0;m<4;m++)
    #pragma unroll
    for (int n=0;n<4;n++) acc[m][n]=zero;
  const size_t rowA = (size_t)(bm + w*32 + (lane>>2))*K + (lane&3)*8;
  const size_t rowB = (size_t)(bn + w*32 + (lane>>2))*K + (lane&3)*8;
  unsigned short* lA = As + w*32*32;
  unsigned short* lB = Bs + w*32*32;
  for (int k0=0; k0<K; k0+=32){
    GLDS16(A + rowA + k0,                 lA);
    GLDS16(A + rowA + k0 + (size_t)16*K,  lA + 512);
    GLDS16(Bt + rowB + k0,                lB);
    GLDS16(Bt + rowB + k0 + (size_t)16*K, lB + 512);
    __syncthreads();
    bf16x8 af[4], bfr[4];
    #pragma unroll
    for (int m=0;m<4;m++) af[m]  = *(const bf16x8*)(void*)(As + (wr*64+m*16+lr)*32 + kg*8);
    #pragma unroll
    for (int n=0;n<4;n++) bfr[n] = *(const bf16x8*)(void*)(Bs + (wc*64+n*16+lr)*32 + kg*8);
    #pragma unroll
    for (int m=0;m<4;m++)
      #pragma unroll
      for (int n=0;n<4;n++)
        acc[m][n] = __builtin_amdgcn_mfma_f32_16x16x32_bf16(af[m], bfr[n], acc[m][n], 0,0,0);
    __syncthreads();
  }
  #pragma unroll
  for (int m=0;m<4;m++)
    #pragma unroll
    for (int n=0;n<4;n++){
      size_t r0 = (size_t)(bm + wr*64 + m*16 + kg*4);
      int cc = bn + wc*64 + n*16 + lr;
      #pragma unroll
      for (int q=0;q<4;q++)
        C[(r0+q)*N + cc] = __float2bfloat16(acc[m][n][q]);
    }
}

// ---------------- K2b: mix, 8 rows per block (tm pre-tanh'd) ----------------
__global__ __launch_bounds__(256) void k2_mix(const float* __restrict__ x, const float* __restrict__ xx,
    const float* __restrict__ tm, const float* __restrict__ w2,
    const float* __restrict__ mrg, const float* __restrict__ mwa,
    const float* __restrict__ mk_, const float* __restrict__ mv_,
    bf16* __restrict__ xrg, bf16* __restrict__ xwa, bf16* __restrict__ xk, bf16* __restrict__ xv) {
  const int row0 = blockIdx.x*8, tid = threadIdx.x;
  __shared__ float stm[8][112];
  for (int idx=tid; idx<8*112; idx+=256){
    int rr=idx/112, q=idx-rr*112;
    stm[rr][q]=tm[(size_t)(row0+rr)*112+q];
  }
  __syncthreads();
  for (int c=tid;c<Cdim;c+=256){
    float x8[8], d8[8];
    #pragma unroll
    for (int rr=0;rr<8;rr++){
      size_t i=(size_t)(row0+rr)*Cdim+c;
      x8[rr]=x[i]; d8[rr]=xx[i];
    }
    float mrgc=mrg[c], mwac=mwa[c], mkc=mk_[c], mvc=mv_[c];
    float m0[8]={},m1[8]={},m2[8]={},m3[8]={};
    #pragma unroll 4
    for (int d=0; d<28; d++){
      float w0=w2[(size_t)(d)*Cdim + c];
      float w1=w2[(size_t)(28+d)*Cdim + c];
      float w2v=w2[(size_t)(56+d)*Cdim + c];
      float w3=w2[(size_t)(84+d)*Cdim + c];
      #pragma unroll
      for (int rr=0;rr<8;rr++){
        m0[rr]+=stm[rr][d]*w0; m1[rr]+=stm[rr][28+d]*w1;
        m2[rr]+=stm[rr][56+d]*w2v; m3[rr]+=stm[rr][84+d]*w3;
      }
    }
    #pragma unroll
    for (int rr=0;rr<8;rr++){
      size_t i=(size_t)(row0+rr)*Cdim+c;
      xrg[i]=__float2bfloat16(x8[rr] + d8[rr]*(mrgc+m0[rr]));
      xwa[i]=__float2bfloat16(x8[rr] + d8[rr]*(mwac+m1[rr]));
      xk[i] =__float2bfloat16(x8[rr] + d8[rr]*(mkc+m2[rr]));
      xv[i] =__float2bfloat16(x8[rr] + d8[rr]*(mvc+m3[rr]));
    }
  }
}

// ---------------- K5 v3: pure elementwise + in-wave head norm ----------------
__global__ __launch_bounds__(256) void k5_fuse(
    const bf16* __restrict__ zwa, const bf16* __restrict__ zk, const bf16* __restrict__ zv,
    const float* __restrict__ td, const float* __restrict__ aaaaa,
    const float* __restrict__ misc_a, const float* __restrict__ misc_k, const float* __restrict__ misc_v,
    const float* __restrict__ v1,
    float* __restrict__ kbuf, float* __restrict__ vbuf, float* __restrict__ wexp,
    bf16* __restrict__ kb_bf, bf16* __restrict__ vb_bf,
    bf16* __restrict__ akv, bf16* __restrict__ bkv) {
  const int row = blockIdx.x, tid = threadIdx.x;
  float kraw[3], v0[3], v1v[3];
  #pragma unroll
  for (int it=0;it<3;it++){
    size_t i=(size_t)row*Cdim + tid + it*256;
    kraw[it]=kbuf[i]; v0[it]=vbuf[i]; v1v[it]=v1[i];
  }
  __syncthreads();   // all f32 reads of kbuf/vbuf done before bf16 overlay writes
  #pragma unroll
  for (int it=0;it<3;it++){
    const int c = tid + it*256;
    const size_t i=(size_t)row*Cdim+c;
    float zd = bf2f(zwa[(size_t)row*2304 + c]);
    float za = bf2f(zwa[(size_t)row*2304 + 768 + c]);
    float zma= bf2f(zwa[(size_t)row*2304 + 1536 + c]);
    float zkk= bf2f(zk[(size_t)row*1536 + c]);
    float zmk= bf2f(zk[(size_t)row*1536 + 768 + c]);
    float zmv= bf2f(zv[i]);
    float w = -softplusf(-(td[c]+zd)) - 0.5f;
    wexp[i] = expf(-expf(w));
    float a  = sigm(aaaaa[c]+za);
    float ma = sigm(misc_a[c]+zma);
    float mk = sigm(misc_k[c]+zmk);
    float mv = sigm(misc_v[c]+zmv);
    vb_bf[i] = __float2bfloat16(v0[it] + (v1v[it]-v0[it])*mv);
    float kf = kraw[it]*(ma + a*(1.f-ma))*expf(fminf(w*mk,0.f));
    kb_bf[i] = __float2bfloat16(kf);
    float kk = kraw[it] + zkk;
    float ss = red32(kk*kk);
    float kkn = kk * (1.f/fmaxf(sqrtf(ss),1e-12f));
    akv[i] = __float2bfloat16(-kkn);
    bkv[i] = __float2bfloat16(kkn*a);
  }
}

// ---------------- K6 v8: 8 blocks/head, depth-2 ping-pong register prefetch ----------------
// wave = 4 rows x 16 lanes (2 elems/lane). Wave-private GLDS, raw vmcnt(0), all-DPP red16.
// pA serves even steps, pB odd steps; each step reloads its own set for t+2 -> LDS latency
// gets ~2 compute-steps to hide, no v_mov ping-pong overhead.
struct TReg { unsigned r,k,a,b; float2 w; unsigned short v; };
__global__ __launch_bounds__(64) void k6_wkv(const unsigned short* __restrict__ r, const float* __restrict__ wd,
    const unsigned short* __restrict__ k, const unsigned short* __restrict__ v,
    const unsigned short* __restrict__ a, const unsigned short* __restrict__ b2, float* __restrict__ y) {
  const int lane = threadIdx.x;
  const int bid = blockIdx.x;
  const int head = bid % (Bdim*Hdim);        // 0..191 (keeps a head's 8 blocks on one XCD)
  const int rq   = bid / (Bdim*Hdim);        // 0..7
  const int bb = head / Hdim, hh = head - bb*Hdim;
  const int i0 = rq*4 + (lane >> 4);         // global row
  const int jh = lane & 15;
  const int col = jh*2;
  __shared__ __align__(16) float swd[2][CH6][Ndim];
  __shared__ __align__(16) unsigned short sbf[2][4][CH6][Ndim];
  __shared__ __align__(16) unsigned short sv2[2][CH6][Ndim];
  const unsigned short* gb16[4] = {r, k, a, b2};
  const size_t gbase = (size_t)bb*Tdim*Cdim + (size_t)hh*Ndim;
  float S0=0.f, S1=0.f;

  auto STAGE = [&](int c, int buf){
    const size_t tb = (size_t)c*CH6;
    GLDS16(wd + gbase + (tb +   (lane>>3))*Cdim + (lane&7)*4, &swd[buf][0][0]);
    GLDS16(wd + gbase + (tb + 8+(lane>>3))*Cdim + (lane&7)*4, &swd[buf][8][0]);
    #pragma unroll
    for (int arr=0; arr<4; arr++)
      GLDS16(gb16[arr] + gbase + (tb + (lane>>2))*Cdim + (lane&3)*8, &sbf[buf][arr][0][0]);
    GLDS16(v + gbase + (tb + (lane>>2))*Cdim + (lane&3)*8, &sv2[buf][0][0]);
  };

  auto LOADT = [&](TReg& d, int buf, int t){
    d.r = *(const unsigned*)&sbf[buf][0][t][col];
    d.k = *(const unsigned*)&sbf[buf][1][t][col];
    d.a = *(const unsigned*)&sbf[buf][2][t][col];
    d.b = *(const unsigned*)&sbf[buf][3][t][col];
    d.w = *(const float2*)&swd[buf][t][col];
    d.v = sv2[buf][t][i0];
  };

  STAGE(0, 0);
  asm volatile("s_waitcnt vmcnt(0)" ::: "memory");
  TReg pA, pB;
  LOADT(pA, 0, 0);
  LOADT(pB, 0, 1);
  int buf = 0;
  const int NCH = Tdim/CH6;
  for (int c=0; c<NCH; ++c){
    if (c+1 < NCH) STAGE(c+1, buf^1);
    const size_t yb = gbase + (size_t)c*CH6*Cdim;
    #pragma unroll
    for (int t=0; t<CH6; t++){
      TReg& cur = (t&1) ? pB : pA;
      const unsigned cr=cur.r, ck=cur.k, ca=cur.a, cb=cur.b;
      const float2 cw=cur.w;
      const unsigned short cv=cur.v;
      // depth-2 prefetch into the set just consumed
      const int tt = t+2;
      if (tt < CH6) {
        LOADT(cur, buf, tt);
      } else if (c+1 < NCH) {
        if (tt == CH6) asm volatile("s_waitcnt vmcnt(0)" ::: "memory");
        LOADT(cur, buf^1, tt-CH6);
      }
      float a0 = __builtin_bit_cast(float, ca<<16);
      float a1 = __builtin_bit_cast(float, ca&0xFFFF0000u);
      float sa = S0*a0 + S1*a1;
      sa = red16(sa);
      float k0 = __builtin_bit_cast(float, ck<<16);
      float k1 = __builtin_bit_cast(float, ck&0xFFFF0000u);
      float b0 = __builtin_bit_cast(float, cb<<16);
      float b1 = __builtin_bit_cast(float, cb&0xFFFF0000u);
      float r0 = __builtin_bit_cast(float, cr<<16);
      float r1 = __builtin_bit_cast(float, cr&0xFFFF0000u);
      const float vl = us2f(cv);
      S0 = S0*cw.x + (sa*b0 + vl*k0);
      S1 = S1*cw.y + (sa*b1 + vl*k1);
      float yv = S0*r0 + S1*r1;
      yv = red16(yv);
      if (jh == 0) y[yb + (size_t)t*Cdim + i0] = yv;
    }
    buf ^= 1;
  }
}

// ---------------- K7 v4: GroupNorm + bonus + gate + folded v1 passthrough ----------------
__global__ __launch_bounds__(256) void k7_post(const float* __restrict__ y,
    const bf16* __restrict__ r, const bf16* __restrict__ kf, const bf16* __restrict__ v,
    const bf16* __restrict__ g, const float* __restrict__ faaaa,
    const float* __restrict__ lnw, const float* __restrict__ lnb,
    bf16* __restrict__ ygate,
    const float4* __restrict__ v1c, float4* __restrict__ outc) {
  const int row = blockIdx.x, tid = threadIdx.x;
  if (tid < 192) outc[(size_t)row*192 + tid] = v1c[(size_t)row*192 + tid];
  #pragma unroll
  for (int it=0; it<3; it++){
    const int c = tid + it*256;
    const size_t i = (size_t)row*Cdim + c;
    float yv = y[i];
    float bon = bf2f(r[i])*bf2f(kf[i])*faaaa[c];
    float s  = red32(yv);
    float ss = red32(yv*yv);
    float bn = red32(bon);
    float mu = s*(1.f/Ndim);
    float var = ss*(1.f/Ndim) - mu*mu;
    float rs = rsqrtf(var + 6.4e-5f);
    float yn = (yv-mu)*rs*lnw[c]+lnb[c];
    ygate[i]=__float2bfloat16((yn + bn*bf2f(v[i]))*bf2f(g[i]));
  }
}

extern "C" void kernel_launch(void* const* d_in, const int* in_sizes, int n_in,
                              void* d_out, int out_size, void* d_ws, size_t ws_size,
                              hipStream_t stream) {
  const float* x      = (const float*)d_in[0];
  const float* v1     = (const float*)d_in[1];
  const float* maa_x  = (const float*)d_in[2];
  const float* maa_rg = (const float*)d_in[3];
  const float* maa_wa = (const float*)d_in[4];
  const float* maa_k  = (const float*)d_in[5];
  const float* maa_v  = (const float*)d_in[6];
  const float* time_decay = (const float*)d_in[7];
  const float* faaaa  = (const float*)d_in[8];
  const float* aaaaa  = (const float*)d_in[9];
  const float* maa_w1 = (const float*)d_in[10];
  const float* maa_w2 = (const float*)d_in[11];
  const float* dw1    = (const float*)d_in[12];
  const float* dw2    = (const float*)d_in[13];
  const float* aaa_w1 = (const float*)d_in[14];
  const float* aaa_w2 = (const float*)d_in[15];
  const float* kkk_w1 = (const float*)d_in[16];
  const float* kkk_w2 = (const float*)d_in[17];
  const float* gate_w1= (const float*)d_in[18];
  const float* gate_w2= (const float*)d_in[19];
  const float* ma_w1  = (const float*)d_in[20];
  const float* ma_w2  = (const float*)d_in[21];
  const float* misc_a = (const float*)d_in[22];
  const float* mk_w1  = (const float*)d_in[23];
  const float* mk_w2  = (const float*)d_in[24];
  const float* misc_k = (const float*)d_in[25];
  const float* mv_w1  = (const float*)d_in[26];
  const float* mv_w2  = (const float*)d_in[27];
  const float* misc_v = (const float*)d_in[28];
  const float* Wr     = (const float*)d_in[29];
  const float* Wk     = (const float*)d_in[30];
  const float* Wv     = (const float*)d_in[31];
  const float* Wo     = (const float*)d_in[32];
  const float* lnw    = (const float*)d_in[33];
  const float* lnb    = (const float*)d_in[34];
  float* out = (float*)d_out;

  float* ws = (float*)d_ws;
  const size_t BTC = (size_t)BTdim*Cdim;   // 6291456
  const size_t HB  = BTC/2;                // 3145728
  float* xx   = ws;                float* wexp = ws;
  float* kb   = ws + 2*HB;         bf16* kb_bf = (bf16*)kb;
  float* vb   = ws + 4*HB;         bf16* vb_bf = (bf16*)vb;
  bf16* xrg_bf = (bf16*)(ws + 6*HB);
  bf16* xwa_bf = xrg_bf + BTC;
  bf16* zwa_bf = (bf16*)(ws + 6*HB);
  bf16* xk_bf  = (bf16*)(ws + 9*HB);
  bf16* xv_bf  = xk_bf + BTC;
  bf16* zk_bf  = (bf16*)(ws + 9*HB);
  bf16* xxx_bf = (bf16*)(ws + 11*HB);
  bf16* zv_bf  = (bf16*)(ws + 11*HB);
  float* tm    = ws + 12*HB;
  bf16* zg_bf  = (bf16*)(ws + 12*HB);
  bf16* hwa_bf = (bf16*)(ws + 13*HB);
  bf16* hk_bf  = hwa_bf + (size_t)BTdim*128;
  bf16* hv_bf  = hk_bf  + (size_t)BTdim*64;
  bf16* hrg_bf = hv_bf  + (size_t)BTdim*32;
  bf16* akv_bf = (bf16*)(ws + 13*HB);
  bf16* bkv_bf = (bf16*)(ws + 14*HB);
  bf16* yg_bf  = (bf16*)(ws + 14*HB);
  float* ybuf  = ws + 15*HB;
  bf16* rb_bf  = (bf16*)(ws + 17*HB);
  bf16* Wbase  = (bf16*)(ws + 18*HB);
  bf16* WtR = Wbase;
  bf16* WtK = WtR + 589824;
  bf16* WtV = WtK + 589824;
  bf16* WtO = WtV + 589824;
  bf16* PWwa = WtO + 589824;
  bf16* PWk  = PWwa + 98304;
  bf16* PWv  = PWk  + 98304;
  bf16* PWrg = PWv  + 98304;
  bf16* PWmaa= PWrg + 98304;
  bf16* W2wa = PWmaa + 98304;
  bf16* W2k  = W2wa + 294912;
  bf16* W2v  = W2k  + 98304;
  bf16* W2g  = W2v  + 24576;

  dim3 blk(256);
  kconvW<<<dim3(24,24,4), blk, 0, stream>>>(Wr,Wk,Wv,Wo, WtR,WtK,WtV,WtO);
  kprep<<<dim3(3936), blk, 0, stream>>>(dw1,aaa_w1,ma_w1,kkk_w1,mk_w1,mv_w1,gate_w1,maa_w1,
                                        dw2,aaa_w2,ma_w2,kkk_w2,mk_w2,mv_w2,gate_w2,
                                        PWwa,PWk,PWv,PWrg,PWmaa, W2wa,W2k,W2v,W2g);
  k1_shift<<<dim3((BTdim*Cdim+255)/256), blk, 0, stream>>>(x, maa_x, xx, xxx_bf);
  gemm_tm<<<dim3(1,64), blk, 0, stream>>>(xxx_bf, PWmaa, tm, Cdim);
  k2_mix<<<dim3(BTdim/8), blk, 0, stream>>>(x, xx, tm, maa_w2, maa_rg, maa_wa, maa_k, maa_v,
                                            xrg_bf, xwa_bf, xk_bf, xv_bf);
  {
    S1P p{};
    p.A[0]=xwa_bf; p.Bt[0]=PWwa; p.C[0]=hwa_bf; p.Ntrue[0]=112; p.Nalloc[0]=128; p.act[0]=1;
    p.A[1]=xk_bf;  p.Bt[1]=PWk;  p.C[1]=hk_bf;  p.Ntrue[1]=48;  p.Nalloc[1]=64;  p.act[1]=2;
    p.A[2]=xv_bf;  p.Bt[2]=PWv;  p.C[2]=hv_bf;  p.Ntrue[2]=24;  p.Nalloc[2]=32;  p.act[2]=0;
    p.A[3]=xrg_bf; p.Bt[3]=PWrg; p.C[3]=hrg_bf; p.Ntrue[3]=120; p.Nalloc[3]=128; p.act[3]=3;
    gemm_s1<<<dim3(1,64,4), blk, 0, stream>>>(p, Cdim);
  }
  {
    G3 p{};
    p.A[0]=xrg_bf; p.Bt[0]=WtR; p.Ch[0]=rb_bf; p.Cf[0]=nullptr; p.isbf[0]=1;
    p.A[1]=xk_bf;  p.Bt[1]=WtK; p.Cf[1]=kb;    p.Ch[1]=nullptr; p.isbf[1]=0;
    p.A[2]=xv_bf;  p.Bt[2]=WtV; p.Cf[2]=vb;    p.Ch[2]=nullptr; p.isbf[2]=0;
    gemm_big3<<<dim3(6,64,3), blk, 0, stream>>>(p, Cdim, Cdim);
  }
  {
    Z4 p{};
    p.A[0]=hwa_bf; p.Bt[0]=W2wa; p.C[0]=zwa_bf; p.N[0]=2304; p.K[0]=128;
    p.A[1]=hk_bf;  p.Bt[1]=W2k;  p.C[1]=zk_bf;  p.N[1]=1536; p.K[1]=64;
    p.A[2]=hv_bf;  p.Bt[2]=W2v;  p.C[2]=zv_bf;  p.N[2]=768;  p.K[2]=32;
    p.A[3]=hrg_bf; p.Bt[3]=W2g;  p.C[3]=zg_bf;  p.N[3]=768;  p.K[3]=128;
    gemm_z<<<dim3(18,64,4), blk, 0, stream>>>(p);
  }
  k5_fuse<<<dim3(BTdim), blk, 0, stream>>>(zwa_bf, zk_bf, zv_bf,
      time_decay, aaaaa, misc_a, misc_k, misc_v, v1,
      kb, vb, wexp, kb_bf, vb_bf, akv_bf, bkv_bf);
  k6_wkv<<<dim3(Bdim*Hdim*8), dim3(64), 0, stream>>>((const unsigned short*)rb_bf, wexp,
      (const unsigned short*)kb_bf, (const unsigned short*)vb_bf,
      (const unsigned short*)akv_bf, (const unsigned short*)bkv_bf, ybuf);
  k7_post<<<dim3(BTdim), blk, 0, stream>>>(ybuf, rb_bf, kb_bf, vb_bf, zg_bf, faaaa, lnw, lnb, yg_bf,
                                           (const float4*)v1, (float4*)(out + BTC));
  gemm_mfma<<<dim3(6,64), blk, 0, stream>>>(yg_bf, WtO, out, BTdim, Cdim, Cdim);
}